// Round 1
// baseline (726.829 us; speedup 1.0000x reference)
//
#include <hip/hip_runtime.h>
#include <math.h>

#define NN 65536      // nodes
#define NE 524288     // edges
#define NG 256        // graphs (256 contiguous nodes each)
#define SLOPE 0.01f

__device__ __forceinline__ float lrelu(float v){ return v > 0.f ? v : SLOPE*v; }

// ---------- block reductions (256-thread blocks = 4 waves) ----------
__device__ __forceinline__ float blockMax4(float v, float* s4){
  #pragma unroll
  for(int o=32;o>0;o>>=1) v = fmaxf(v, __shfl_down(v, o, 64));
  int t = threadIdx.x;
  __syncthreads();                 // protect s4 reuse from previous call
  if((t&63)==0) s4[t>>6] = v;
  __syncthreads();
  return fmaxf(fmaxf(s4[0], s4[1]), fmaxf(s4[2], s4[3]));
}
__device__ __forceinline__ float blockSum4(float v, float* s4){
  #pragma unroll
  for(int o=32;o>0;o>>=1) v += __shfl_down(v, o, 64);
  int t = threadIdx.x;
  __syncthreads();
  if((t&63)==0) s4[t>>6] = v;
  __syncthreads();
  return (s4[0]+s4[1])+(s4[2]+s4[3]);
}

// ---------- CSR build (by dst) ----------
__global__ __launch_bounds__(256) void k_count(const int* __restrict__ ei, int* __restrict__ deg){
  int e = blockIdx.x*256 + threadIdx.x;
  if(e < NE) atomicAdd(&deg[ei[NE + e]], 1);
}

__global__ __launch_bounds__(1024) void k_scan(const int* __restrict__ deg,
      int* __restrict__ offs, int* __restrict__ cursor){
  __shared__ int part[1024];
  int t = threadIdx.x;
  int base = t*64;
  int s=0;
  for(int i=0;i<64;i++) s += deg[base+i];
  part[t]=s;
  __syncthreads();
  for(int off=1; off<1024; off<<=1){
    int v = (t>=off)? part[t-off] : 0;
    __syncthreads();
    part[t] += v;
    __syncthreads();
  }
  int run = (t==0)? 0 : part[t-1];
  for(int i=0;i<64;i++){
    int d = deg[base+i];
    offs[base+i] = run; cursor[base+i] = run;
    run += d;
  }
  if(t==1023) offs[NN] = run;
}

__global__ __launch_bounds__(256) void k_scatter(const int* __restrict__ ei,
      int* __restrict__ cursor, int* __restrict__ csr){
  int e = blockIdx.x*256 + threadIdx.x;
  if(e < NE){
    int d = ei[NE + e];
    int p = atomicAdd(&cursor[d], 1);
    csr[p] = ei[e];
  }
}

// ---------- conv0: agg[i] = max over in-edges of x[src], else 0 ----------
__global__ __launch_bounds__(256) void k_agg0(const float* __restrict__ x,
    const int* __restrict__ offs, const int* __restrict__ csr, float* __restrict__ agg0){
  int tid = blockIdx.x*256 + threadIdx.x;
  int node = tid>>4, q = tid&15;        // 16 threads (float4 lanes) per node
  int e0 = offs[node], e1 = offs[node+1];
  float4 acc = make_float4(0.f,0.f,0.f,0.f);
  if(e0 < e1){
    acc = make_float4(-INFINITY,-INFINITY,-INFINITY,-INFINITY);
    for(int e=e0;e<e1;e++){
      int s = csr[e];
      float4 v = ((const float4*)x)[s*16 + q];
      acc.x=fmaxf(acc.x,v.x); acc.y=fmaxf(acc.y,v.y);
      acc.z=fmaxf(acc.z,v.z); acc.w=fmaxf(acc.w,v.w);
    }
  }
  ((float4*)agg0)[node*16 + q] = acc;
}

// ---------- conv0 matmul: cur = lrelu(agg0@Wrel^T + x@Wroot^T + b0) ----------
// lane = node (64 nodes per wave-tile). Rows (agg|x, 32 float4 chunks) in LDS with
// XOR swizzle -> conflict-free ds_read_b128. W addresses are wave-uniform -> s_load.
__global__ __launch_bounds__(128) void k_conv0mm(
    const float* __restrict__ agg0, const float* __restrict__ x,
    const float* __restrict__ Wrel, const float* __restrict__ Wroot,
    const float* __restrict__ b0, float* __restrict__ cur){
  __shared__ float4 rows[2][64][32];   // 64 KB
  const int t = threadIdx.x, w = t>>6, l = t&63;
  const int nwave = gridDim.x*2;
  for(int tile = blockIdx.x*2 + w; tile < NN/64; tile += nwave){
    const int nbase = tile*64;
    #pragma unroll
    for(int i=0;i<16;i++){
      int idx = i*64 + l;
      int nn = idx>>4, q = idx&15;
      rows[w][nn][(q+nn)&31]    = ((const float4*)agg0)[(nbase+nn)*16 + q];
      rows[w][nn][(16+q+nn)&31] = ((const float4*)x   )[(nbase+nn)*16 + q];
    }
    const int n = nbase + l;
    #pragma unroll 1
    for(int jt=0; jt<8; jt++){
      float acc[16];
      #pragma unroll
      for(int jj=0;jj<16;jj++) acc[jj] = b0[jt*16+jj];
      #pragma unroll 4
      for(int c=0;c<16;c++){
        float4 v = rows[w][l][(c+l)&31];
        #pragma unroll
        for(int jj=0;jj<16;jj++){
          const float* p = Wrel + (jt*16+jj)*64 + c*4;   // uniform -> s_load
          acc[jj] = fmaf(v.x,p[0], fmaf(v.y,p[1], fmaf(v.z,p[2], fmaf(v.w,p[3], acc[jj]))));
        }
      }
      #pragma unroll 4
      for(int c=0;c<16;c++){
        float4 v = rows[w][l][(16+c+l)&31];
        #pragma unroll
        for(int jj=0;jj<16;jj++){
          const float* p = Wroot + (jt*16+jj)*64 + c*4;  // uniform -> s_load
          acc[jj] = fmaf(v.x,p[0], fmaf(v.y,p[1], fmaf(v.z,p[2], fmaf(v.w,p[3], acc[jj]))));
        }
      }
      #pragma unroll
      for(int j4=0;j4<4;j4++){
        float4 o;
        o.x = lrelu(acc[j4*4+0]); o.y = lrelu(acc[j4*4+1]);
        o.z = lrelu(acc[j4*4+2]); o.w = lrelu(acc[j4*4+3]);
        ((float4*)cur)[n*32 + jt*4 + j4] = o;
      }
    }
  }
}

// ---------- batchnorm stats over cur [NN x 128] ----------
__global__ __launch_bounds__(256) void k_bnstats(const float* __restrict__ cur,
                        float* __restrict__ bnsum, float* __restrict__ bnsq){
  __shared__ __align__(16) float4 rs[8][32];
  __shared__ __align__(16) float4 rq[8][32];
  int t = threadIdx.x, col = t&31, rowg = t>>5;
  float4 s = make_float4(0.f,0.f,0.f,0.f), q = make_float4(0.f,0.f,0.f,0.f);
  for(int i = blockIdx.x*8 + rowg; i < NN; i += gridDim.x*8){
    float4 v = ((const float4*)cur)[i*32 + col];
    s.x+=v.x; s.y+=v.y; s.z+=v.z; s.w+=v.w;
    q.x+=v.x*v.x; q.y+=v.y*v.y; q.z+=v.z*v.z; q.w+=v.w*v.w;
  }
  rs[rowg][col]=s; rq[rowg][col]=q;
  __syncthreads();
  if(t<32){
    float4 S=make_float4(0.f,0.f,0.f,0.f), Q=make_float4(0.f,0.f,0.f,0.f);
    #pragma unroll
    for(int k=0;k<8;k++){
      float4 a=rs[k][t], b=rq[k][t];
      S.x+=a.x;S.y+=a.y;S.z+=a.z;S.w+=a.w;
      Q.x+=b.x;Q.y+=b.y;Q.z+=b.z;Q.w+=b.w;
    }
    atomicAdd(&bnsum[t*4+0],S.x); atomicAdd(&bnsum[t*4+1],S.y);
    atomicAdd(&bnsum[t*4+2],S.z); atomicAdd(&bnsum[t*4+3],S.w);
    atomicAdd(&bnsq[t*4+0],Q.x);  atomicAdd(&bnsq[t*4+1],Q.y);
    atomicAdd(&bnsq[t*4+2],Q.z);  atomicAdd(&bnsq[t*4+3],Q.w);
  }
}

// ---------- apply bn0 in place ----------
__global__ __launch_bounds__(256) void k_applybn0(float* __restrict__ cur,
    const float* __restrict__ bnsum, const float* __restrict__ bnsq,
    const float* __restrict__ gg, const float* __restrict__ bb){
  __shared__ __align__(16) float sc[128];
  __shared__ __align__(16) float of[128];
  int t = threadIdx.x;
  if(t<128){
    float mu = bnsum[t]*(1.0f/NN);
    float var = bnsq[t]*(1.0f/NN) - mu*mu;
    float rs = rsqrtf(var+1e-5f);
    float s = gg[t]*rs;
    sc[t]=s; of[t]=bb[t]-mu*s;
  }
  __syncthreads();
  int tid = blockIdx.x*256 + t;
  int q = tid&31;
  float4 v = ((const float4*)cur)[tid];
  float4 s4 = *(const float4*)&sc[q*4];
  float4 o4 = *(const float4*)&of[q*4];
  v.x = s4.x*v.x + o4.x; v.y = s4.y*v.y + o4.y;
  v.z = s4.z*v.z + o4.z; v.w = s4.w*v.w + o4.w;
  ((float4*)cur)[tid] = v;
}

// ---------- TopK pool for one block-layer: 4 heads at once ----------
__global__ __launch_bounds__(256) void k_pool(const float* __restrict__ cur,
    const float* __restrict__ pw, float minscore,
    float* __restrict__ sm4, unsigned char* __restrict__ keep,
    int* __restrict__ cnt, int* __restrict__ wl){
  __shared__ __align__(16) float w[4][128];
  __shared__ float red[4];
  int t = threadIdx.x, g = blockIdx.x;
  for(int i=t;i<512;i+=256) w[i>>7][i&127] = pw[i];
  __syncthreads();
  int n = g*256 + t;
  const float4* row = (const float4*)(cur + (size_t)n*128);
  float sc[4] = {0.f,0.f,0.f,0.f};
  for(int k=0;k<32;k++){
    float4 v = row[k];
    #pragma unroll
    for(int h=0;h<4;h++){
      const float4 wv = *(const float4*)&w[h][k*4];
      sc[h] += v.x*wv.x + v.y*wv.y + v.z*wv.z + v.w*wv.w;
    }
  }
  float4 smout;
  unsigned kb = 0;
  #pragma unroll 1
  for(int h=0;h<4;h++){
    float m = blockMax4(sc[h], red);
    float e = expf(sc[h]-m);
    float ssum = blockSum4(e, red);
    float sm = e/(ssum + 1e-16f);
    float smax = blockMax4(sm, red);
    float thr = fminf(smax - 1e-7f, minscore);
    ((float*)&smout)[h] = sm;
    if(sm > thr){
      kb |= (1u<<h);
      int p = atomicAdd(cnt, 1);
      wl[p] = (h<<16) | n;           // (head, node)
    }
  }
  ((float4*)sm4)[n] = smout;
  keep[n] = (unsigned char)kb;
}

// ---------- block-layer GraphConv(max) on kept (head,node) work items ----------
__global__ __launch_bounds__(256) void k_blockconv(const float* __restrict__ cur,
    const int* __restrict__ offs, const int* __restrict__ csr,
    const unsigned char* __restrict__ keep, const float* __restrict__ sm4,
    const int* __restrict__ cnt, const int* __restrict__ wl,
    const float* __restrict__ Wrel, const float* __restrict__ Wroot,
    const float* __restrict__ bias,
    float* __restrict__ onew, float* __restrict__ bnsum, float* __restrict__ bnsq){
  __shared__ __align__(16) float aggs[8][128];
  __shared__ __align__(16) float xps[8][128];
  const int t = threadIdx.x, grp = t>>5, lane = t&31;   // half-wave groups
  const int total = *cnt;
  for(int item = blockIdx.x*8 + grp; item < total; item += gridDim.x*8){
    const int wv = wl[item];
    const int h = wv>>16, n = wv & 0xFFFF;
    const float smn = sm4[n*4+h];
    const int e0 = offs[n], e1 = offs[n+1];
    float4 acc = make_float4(-INFINITY,-INFINITY,-INFINITY,-INFINITY);
    bool any = false;
    for(int e=e0;e<e1;e++){
      int s = csr[e];
      if((keep[s]>>h)&1){
        any = true;
        float sv = sm4[s*4+h];
        float4 v = ((const float4*)cur)[s*32 + lane];
        acc.x = fmaxf(acc.x, v.x*sv); acc.y = fmaxf(acc.y, v.y*sv);
        acc.z = fmaxf(acc.z, v.z*sv); acc.w = fmaxf(acc.w, v.w*sv);
      }
    }
    if(!any) acc = make_float4(0.f,0.f,0.f,0.f);
    *(float4*)&aggs[grp][lane*4] = acc;
    float4 xv = ((const float4*)cur)[n*32 + lane];
    xv.x*=smn; xv.y*=smn; xv.z*=smn; xv.w*=smn;
    *(float4*)&xps[grp][lane*4] = xv;
    // group = half-wave: LDS write->read within one wave is program-ordered, no barrier
    const float* Wr = Wrel  + (size_t)(h*32+lane)*128;
    const float* Wo = Wroot + (size_t)(h*32+lane)*128;
    float o = bias[h*32+lane];
    for(int k=0;k<32;k++){
      float4 a  = *(const float4*)&aggs[grp][k*4];
      float4 xx = *(const float4*)&xps[grp][k*4];
      float4 wr = ((const float4*)Wr)[k];
      float4 wo = ((const float4*)Wo)[k];
      o += a.x*wr.x + a.y*wr.y + a.z*wr.z + a.w*wr.w;
      o += xx.x*wo.x + xx.y*wo.y + xx.z*wo.z + xx.w*wo.w;
    }
    o = lrelu(o);
    onew[(size_t)n*128 + h*32 + lane] = o;
    atomicAdd(&bnsum[h*32+lane], o);
    atomicAdd(&bnsq[h*32+lane], o*o);
  }
}

// ---------- residual update: cur = 0.5*cur + 0.25*bn(new) ----------
__global__ __launch_bounds__(256) void k_update(float* __restrict__ cur,
    const float* __restrict__ onew, const unsigned char* __restrict__ keep,
    const float* __restrict__ bnsum, const float* __restrict__ bnsq,
    const float* __restrict__ gg, const float* __restrict__ bb){
  __shared__ __align__(16) float sc[128];
  __shared__ __align__(16) float of[128];
  int t = threadIdx.x;
  if(t<128){
    float mu = bnsum[t]*(1.0f/NN);
    float var = bnsq[t]*(1.0f/NN) - mu*mu;
    float rs = rsqrtf(var+1e-5f);
    float s = gg[t]*rs;
    sc[t]=s; of[t]=bb[t]-mu*s;
  }
  __syncthreads();
  int tid = blockIdx.x*256 + t;
  int n = tid>>5, q = tid&31, h = q>>3;
  float4 v = ((const float4*)cur)[tid];
  float4 nv = make_float4(0.f,0.f,0.f,0.f);
  if((keep[n]>>h)&1) nv = ((const float4*)onew)[tid];
  float4 s4 = *(const float4*)&sc[q*4];
  float4 o4 = *(const float4*)&of[q*4];
  v.x = 0.5f*v.x + 0.25f*(s4.x*nv.x + o4.x);
  v.y = 0.5f*v.y + 0.25f*(s4.y*nv.y + o4.y);
  v.z = 0.5f*v.z + 0.25f*(s4.z*nv.z + o4.z);
  v.w = 0.5f*v.w + 0.25f*(s4.w*nv.w + o4.w);
  ((float4*)cur)[tid] = v;
}

// ---------- classification heads: pool + attention + MLP + log_softmax ----------
__global__ __launch_bounds__(256) void k_cls(const float* __restrict__ cur,
    const float* __restrict__ pw,
    const float* __restrict__ gW1, const float* __restrict__ gb1,
    const float* __restrict__ gW2, const float* __restrict__ gb2,
    const float* __restrict__ fW1, const float* __restrict__ fb1,
    const float* __restrict__ fW2, const float* __restrict__ fb2,
    float* __restrict__ out){
  __shared__ __align__(16) float w[4][128];
  __shared__ float red[4];
  __shared__ int keptL[256];
  __shared__ float keptS[256];
  __shared__ float gateL[256];
  __shared__ __align__(16) float xk[128];
  __shared__ __align__(16) float pooled[128];
  __shared__ float yv[4];
  __shared__ int nkept;
  const int t = threadIdx.x, g = blockIdx.x;
  for(int i=t;i<512;i+=256) w[i>>7][i&127] = pw[i];
  __syncthreads();
  const int n = g*256 + t;
  const float4* row = (const float4*)(cur + (size_t)n*128);
  float sc4[4]={0.f,0.f,0.f,0.f};
  for(int k=0;k<32;k++){
    float4 v = row[k];
    #pragma unroll
    for(int c=0;c<4;c++){
      const float4 wv = *(const float4*)&w[c][k*4];
      sc4[c] += v.x*wv.x + v.y*wv.y + v.z*wv.z + v.w*wv.w;
    }
  }
  #pragma unroll 1
  for(int c=0;c<4;c++){
    float m = blockMax4(sc4[c], red);
    float e = expf(sc4[c]-m);
    float ssum = blockSum4(e, red);
    float sm = e/(ssum+1e-16f);
    float smax = blockMax4(sm, red);
    float thr = fminf(smax - 1e-7f, 0.8f);
    if(t==0) nkept = 0;
    __syncthreads();
    if(sm > thr){
      int p = atomicAdd(&nkept,1);
      keptL[p]=t; keptS[p]=sm;
    }
    __syncthreads();
    const int K = nkept;
    for(int k=0;k<K;k++){
      int ln = keptL[k]; float sv = keptS[k];
      if(t<32){
        float4 v = ((const float4*)(cur + (size_t)(g*256+ln)*128))[t];
        v.x*=sv; v.y*=sv; v.z*=sv; v.w*=sv;
        *(float4*)&xk[t*4] = v;
      }
      __syncthreads();
      float part = 0.f;
      if(t<128){
        const float* W = gW1 + (size_t)c*16384 + (size_t)t*128;
        float a = gb1[c*128+t];
        for(int f=0;f<32;f++){
          float4 xv = *(const float4*)&xk[f*4];
          float4 wv = ((const float4*)W)[f];
          a += xv.x*wv.x + xv.y*wv.y + xv.z*wv.z + xv.w*wv.w;
        }
        part = lrelu(a) * gW2[c*128+t];
      }
      float gs = blockSum4(part, red);
      if(t==0) gateL[k] = gs + gb2[c];
      __syncthreads();
    }
    float gv = (t<K)? gateL[t] : -INFINITY;
    float gm = blockMax4(gv, red);
    float ge = (t<K)? expf(gv-gm) : 0.f;
    float gsum = blockSum4(ge, red);
    if(t<K) gateL[t] = ge/(gsum+1e-16f);
    __syncthreads();
    if(t<128){
      float acc = 0.f;
      for(int k=0;k<K;k++)
        acc += gateL[k]*keptS[k]*cur[(size_t)(g*256+keptL[k])*128 + t];
      pooled[t]=acc;
    }
    __syncthreads();
    float part2=0.f;
    if(t<128){
      const float* F = fW1 + (size_t)c*16384 + (size_t)t*128;
      float a = fb1[c*128+t];
      for(int f=0;f<32;f++){
        float4 xv = *(const float4*)&pooled[f*4];
        float4 wv = ((const float4*)F)[f];
        a += xv.x*wv.x + xv.y*wv.y + xv.z*wv.z + xv.w*wv.w;
      }
      part2 = lrelu(a) * fW2[c*128+t];
    }
    float ysum = blockSum4(part2, red);
    if(t==0) yv[c] = ysum + fb2[c];
    __syncthreads();
  }
  if(t<4){
    float m = fmaxf(fmaxf(yv[0],yv[1]), fmaxf(yv[2],yv[3]));
    float l = logf(expf(yv[0]-m)+expf(yv[1]-m)+expf(yv[2]-m)+expf(yv[3]-m));
    out[g*4+t] = yv[t] - m - l;
  }
}

extern "C" void kernel_launch(void* const* d_in, const int* in_sizes, int n_in,
                              void* d_out, int out_size, void* d_ws, size_t ws_size,
                              hipStream_t stream){
  (void)in_sizes; (void)n_in; (void)out_size; (void)ws_size;
  const float* x     = (const float*)d_in[0];
  const int*   ei    = (const int*)d_in[1];
  const float* Wrel0 = (const float*)d_in[3];
  const float* Wroot0= (const float*)d_in[4];
  const float* b0    = (const float*)d_in[5];
  const float* bn0g  = (const float*)d_in[6];
  const float* bn0b  = (const float*)d_in[7];
  const float* bpw   = (const float*)d_in[8];
  const float* bWrel = (const float*)d_in[9];
  const float* bWroot= (const float*)d_in[10];
  const float* bbv   = (const float*)d_in[11];
  const float* bbng  = (const float*)d_in[12];
  const float* bbnb  = (const float*)d_in[13];
  const float* cpw   = (const float*)d_in[14];
  const float* gW1   = (const float*)d_in[15];
  const float* gb1   = (const float*)d_in[16];
  const float* gW2   = (const float*)d_in[17];
  const float* gb2   = (const float*)d_in[18];
  const float* fW1   = (const float*)d_in[19];
  const float* fb1   = (const float*)d_in[20];
  const float* fW2   = (const float*)d_in[21];
  const float* fb2   = (const float*)d_in[22];

  char* ws = (char*)d_ws;
  float* cur   = (float*)(ws + 0);                 // 33.55 MB
  float* onew  = (float*)(ws + 33554432ull);       // 33.55 MB (agg0 aliases first 16.8 MB)
  float* agg0  = onew;
  int*   csr   = (int*)(ws + 67108864ull);         // 2 MB
  float* sm4   = (float*)(ws + 69206016ull);       // 1 MB
  int*   wl    = (int*)(ws + 70254592ull);         // 1 MB (4N items worst case)
  int*   offs  = (int*)(ws + 71303168ull);         // 256 KB + pad
  int*   cursor= (int*)(ws + 71565568ull);         // 256 KB
  unsigned char* keep = (unsigned char*)(ws + 71827712ull); // 64 KB
  char*  Z     = ws + 71893248ull;                 // zero-init region
  int*   deg   = (int*)Z;
  float* bnsum0= (float*)(Z + 262144);
  float* bnsq0 = (float*)(Z + 262656);
  float* bnA   = (float*)(Z + 263168);
  float* bqA   = (float*)(Z + 263680);
  float* bnB   = (float*)(Z + 264192);
  float* bqB   = (float*)(Z + 264704);
  int*   cnt0  = (int*)(Z + 265216);
  int*   cnt1  = (int*)(Z + 265220);

  hipMemsetAsync(Z, 0, 265224, stream);

  // CSR by dst
  k_count  <<<2048,256,0,stream>>>(ei, deg);
  k_scan   <<<1,1024,0,stream>>>(deg, offs, cursor);
  k_scatter<<<2048,256,0,stream>>>(ei, cursor, csr);

  // conv0 -> lrelu -> bn0
  k_agg0    <<<4096,256,0,stream>>>(x, offs, csr, agg0);
  k_conv0mm <<<512,128,0,stream>>>(agg0, x, Wrel0, Wroot0, b0, cur);
  k_bnstats <<<256,256,0,stream>>>(cur, bnsum0, bnsq0);
  k_applybn0<<<8192,256,0,stream>>>(cur, bnsum0, bnsq0, bn0g, bn0b);

  // block layer 0
  k_pool     <<<256,256,0,stream>>>(cur, bpw, 0.7f, sm4, keep, cnt0, wl);
  k_blockconv<<<256,256,0,stream>>>(cur, offs, csr, keep, sm4, cnt0, wl,
                                    bWrel, bWroot, bbv, onew, bnA, bqA);
  k_update   <<<8192,256,0,stream>>>(cur, onew, keep, bnA, bqA, bbng, bbnb);

  // block layer 1
  k_pool     <<<256,256,0,stream>>>(cur, bpw + 512, 0.7f, sm4, keep, cnt1, wl);
  k_blockconv<<<256,256,0,stream>>>(cur, offs, csr, keep, sm4, cnt1, wl,
                                    bWrel + 16384, bWroot + 16384, bbv + 128, onew, bnB, bqB);
  k_update   <<<8192,256,0,stream>>>(cur, onew, keep, bnB, bqB, bbng + 128, bbnb + 128);

  // classification heads + log_softmax
  k_cls<<<256,256,0,stream>>>(cur, cpw, gW1, gb1, gW2, gb2, fW1, fb1, fW2, fb2,
                              (float*)d_out);
}

// Round 2
// 538.404 us; speedup vs baseline: 1.3500x; 1.3500x over previous
//
#include <hip/hip_runtime.h>
#include <math.h>

#define NN 65536      // nodes
#define NE 524288     // edges
#define NG 256        // graphs (256 contiguous nodes each)
#define SLOPE 0.01f

__device__ __forceinline__ float lrelu(float v){ return v > 0.f ? v : SLOPE*v; }

// ---------- block reductions (256-thread blocks = 4 waves) ----------
__device__ __forceinline__ float blockMax4(float v, float* s4){
  #pragma unroll
  for(int o=32;o>0;o>>=1) v = fmaxf(v, __shfl_down(v, o, 64));
  int t = threadIdx.x;
  __syncthreads();
  if((t&63)==0) s4[t>>6] = v;
  __syncthreads();
  return fmaxf(fmaxf(s4[0], s4[1]), fmaxf(s4[2], s4[3]));
}
__device__ __forceinline__ float blockSum4(float v, float* s4){
  #pragma unroll
  for(int o=32;o>0;o>>=1) v += __shfl_down(v, o, 64);
  int t = threadIdx.x;
  __syncthreads();
  if((t&63)==0) s4[t>>6] = v;
  __syncthreads();
  return (s4[0]+s4[1])+(s4[2]+s4[3]);
}

// ---------- CSR build (by dst) ----------
__global__ __launch_bounds__(256) void k_count(const int* __restrict__ ei, int* __restrict__ deg){
  int e = blockIdx.x*256 + threadIdx.x;
  if(e < NE) atomicAdd(&deg[ei[NE + e]], 1);
}

__global__ __launch_bounds__(1024) void k_scan(const int* __restrict__ deg,
      int* __restrict__ offs, int* __restrict__ cursor){
  __shared__ int part[1024];
  int t = threadIdx.x;
  int base = t*64;
  int s=0;
  for(int i=0;i<64;i++) s += deg[base+i];
  part[t]=s;
  __syncthreads();
  for(int off=1; off<1024; off<<=1){
    int v = (t>=off)? part[t-off] : 0;
    __syncthreads();
    part[t] += v;
    __syncthreads();
  }
  int run = (t==0)? 0 : part[t-1];
  for(int i=0;i<64;i++){
    int d = deg[base+i];
    offs[base+i] = run; cursor[base+i] = run;
    run += d;
  }
  if(t==1023) offs[NN] = run;
}

__global__ __launch_bounds__(256) void k_scatter(const int* __restrict__ ei,
      int* __restrict__ cursor, int* __restrict__ csr){
  int e = blockIdx.x*256 + threadIdx.x;
  if(e < NE){
    int d = ei[NE + e];
    int p = atomicAdd(&cursor[d], 1);
    csr[p] = ei[e];
  }
}

// ---------- conv0: agg[i] = max over in-edges of x[src], else 0 ----------
__global__ __launch_bounds__(256) void k_agg0(const float* __restrict__ x,
    const int* __restrict__ offs, const int* __restrict__ csr, float* __restrict__ agg0){
  int tid = blockIdx.x*256 + threadIdx.x;
  int node = tid>>4, q = tid&15;        // 16 threads (float4 lanes) per node
  int e0 = offs[node], e1 = offs[node+1];
  float4 acc = make_float4(0.f,0.f,0.f,0.f);
  if(e0 < e1){
    acc = make_float4(-INFINITY,-INFINITY,-INFINITY,-INFINITY);
    int e = e0;
    for(; e+1 < e1; e += 2){            // 2-edge unroll: two independent gathers in flight
      int s0 = csr[e], s1 = csr[e+1];
      float4 v0 = ((const float4*)x)[s0*16 + q];
      float4 v1 = ((const float4*)x)[s1*16 + q];
      acc.x=fmaxf(acc.x,fmaxf(v0.x,v1.x)); acc.y=fmaxf(acc.y,fmaxf(v0.y,v1.y));
      acc.z=fmaxf(acc.z,fmaxf(v0.z,v1.z)); acc.w=fmaxf(acc.w,fmaxf(v0.w,v1.w));
    }
    if(e < e1){
      int s0 = csr[e];
      float4 v0 = ((const float4*)x)[s0*16 + q];
      acc.x=fmaxf(acc.x,v0.x); acc.y=fmaxf(acc.y,v0.y);
      acc.z=fmaxf(acc.z,v0.z); acc.w=fmaxf(acc.w,v0.w);
    }
  }
  ((float4*)agg0)[node*16 + q] = acc;
}

// ---------- conv0 matmul: cur = lrelu(agg0@Wrel^T + x@Wroot^T + b0) ----------
// LDS-free scalar-operand GEMM: thread = output col j, W row resident in VGPRs
// (128 regs), node's A row is wave-uniform -> readfirstlane forces s_load path;
// inner loop is v_fma_f32 acc, sgpr, vgpr. 4 accumulators break the dep chain.
__global__ __launch_bounds__(256, 3) void k_conv0mm(
    const float* __restrict__ agg0, const float* __restrict__ x,
    const float* __restrict__ Wrel, const float* __restrict__ Wroot,
    const float* __restrict__ b0, float* __restrict__ cur){
  const int t = threadIdx.x;
  const int j = t & 127;                       // output column
  const int s = __builtin_amdgcn_readfirstlane(t >> 7);  // node-slot set (uniform/wave)
  float wreg[128];
  {
    const float4* wr4 = (const float4*)(Wrel + (size_t)j*64);
    const float4* wo4 = (const float4*)(Wroot + (size_t)j*64);
    #pragma unroll
    for(int i=0;i<16;i++){
      *(float4*)&wreg[i*4]    = wr4[i];
      *(float4*)&wreg[64+i*4] = wo4[i];
    }
  }
  const float bj = b0[j];
  const int base = blockIdx.x * 64;            // 1024 blocks x 64 nodes
  #pragma unroll 1
  for(int it=0; it<32; it++){
    const int node = __builtin_amdgcn_readfirstlane(base + it*2 + s);
    const float* __restrict__ ra = agg0 + (size_t)node*64;
    const float* __restrict__ rx = x    + (size_t)node*64;
    float a0=0.f, a1=0.f, a2=0.f, a3=0.f;
    #pragma unroll
    for(int k=0;k<64;k+=4){
      a0 = fmaf(ra[k+0], wreg[k+0], a0);
      a1 = fmaf(ra[k+1], wreg[k+1], a1);
      a2 = fmaf(ra[k+2], wreg[k+2], a2);
      a3 = fmaf(ra[k+3], wreg[k+3], a3);
    }
    #pragma unroll
    for(int k=0;k<64;k+=4){
      a0 = fmaf(rx[k+0], wreg[64+k+0], a0);
      a1 = fmaf(rx[k+1], wreg[64+k+1], a1);
      a2 = fmaf(rx[k+2], wreg[64+k+2], a2);
      a3 = fmaf(rx[k+3], wreg[64+k+3], a3);
    }
    float o = lrelu((a0+a1)+(a2+a3) + bj);
    cur[(size_t)node*128 + j] = o;
  }
}

// ---------- batchnorm stats over cur [NN x 128] ----------
__global__ __launch_bounds__(256) void k_bnstats(const float* __restrict__ cur,
                        float* __restrict__ bnsum, float* __restrict__ bnsq){
  __shared__ __align__(16) float4 rs[8][32];
  __shared__ __align__(16) float4 rq[8][32];
  int t = threadIdx.x, col = t&31, rowg = t>>5;
  float4 s = make_float4(0.f,0.f,0.f,0.f), q = make_float4(0.f,0.f,0.f,0.f);
  for(int i = blockIdx.x*8 + rowg; i < NN; i += gridDim.x*8){
    float4 v = ((const float4*)cur)[i*32 + col];
    s.x+=v.x; s.y+=v.y; s.z+=v.z; s.w+=v.w;
    q.x+=v.x*v.x; q.y+=v.y*v.y; q.z+=v.z*v.z; q.w+=v.w*v.w;
  }
  rs[rowg][col]=s; rq[rowg][col]=q;
  __syncthreads();
  if(t<32){
    float4 S=make_float4(0.f,0.f,0.f,0.f), Q=make_float4(0.f,0.f,0.f,0.f);
    #pragma unroll
    for(int k=0;k<8;k++){
      float4 a=rs[k][t], b=rq[k][t];
      S.x+=a.x;S.y+=a.y;S.z+=a.z;S.w+=a.w;
      Q.x+=b.x;Q.y+=b.y;Q.z+=b.z;Q.w+=b.w;
    }
    atomicAdd(&bnsum[t*4+0],S.x); atomicAdd(&bnsum[t*4+1],S.y);
    atomicAdd(&bnsum[t*4+2],S.z); atomicAdd(&bnsum[t*4+3],S.w);
    atomicAdd(&bnsq[t*4+0],Q.x);  atomicAdd(&bnsq[t*4+1],Q.y);
    atomicAdd(&bnsq[t*4+2],Q.z);  atomicAdd(&bnsq[t*4+3],Q.w);
  }
}

// ---------- TopK pool: 4 heads at once; optional bn0 fold (scale only —
// per-graph-constant offset term cancels in softmax) ----------
__global__ __launch_bounds__(256) void k_pool(const float* __restrict__ cur,
    const float* __restrict__ pw, float minscore,
    float* __restrict__ sm4, unsigned char* __restrict__ keep,
    int* __restrict__ cnt, int* __restrict__ wl,
    const float* __restrict__ bnsum, const float* __restrict__ bnsq,
    const float* __restrict__ gg, int fold){
  __shared__ __align__(16) float w[4][128];
  __shared__ float red[4];
  __shared__ float scv[128];
  int t = threadIdx.x, g = blockIdx.x;
  if(t<128){
    float sv = 1.f;
    if(fold){
      float mu = bnsum[t]*(1.0f/NN);
      float var = bnsq[t]*(1.0f/NN) - mu*mu;
      sv = gg[t]*rsqrtf(var+1e-5f);
    }
    scv[t] = sv;
  }
  __syncthreads();
  for(int i=t;i<512;i+=256) w[i>>7][i&127] = pw[i]*scv[i&127];
  __syncthreads();
  int n = g*256 + t;
  const float4* row = (const float4*)(cur + (size_t)n*128);
  float sc[4] = {0.f,0.f,0.f,0.f};
  for(int k=0;k<32;k++){
    float4 v = row[k];
    #pragma unroll
    for(int h=0;h<4;h++){
      const float4 wv = *(const float4*)&w[h][k*4];
      sc[h] += v.x*wv.x + v.y*wv.y + v.z*wv.z + v.w*wv.w;
    }
  }
  float4 smout;
  unsigned kb = 0;
  #pragma unroll 1
  for(int h=0;h<4;h++){
    float m = blockMax4(sc[h], red);
    float e = expf(sc[h]-m);
    float ssum = blockSum4(e, red);
    float sm = e/(ssum + 1e-16f);
    float smax = blockMax4(sm, red);
    float thr = fminf(smax - 1e-7f, minscore);
    ((float*)&smout)[h] = sm;
    if(sm > thr){
      kb |= (1u<<h);
      int p = atomicAdd(cnt, 1);
      wl[p] = (h<<16) | n;
    }
  }
  ((float4*)sm4)[n] = smout;
  keep[n] = (unsigned char)kb;
}

// ---------- block-layer GraphConv(max) on kept (head,node) items; optional
// bn0 fold applied to gathered cur rows ----------
__global__ __launch_bounds__(256) void k_blockconv(const float* __restrict__ cur,
    const int* __restrict__ offs, const int* __restrict__ csr,
    const unsigned char* __restrict__ keep, const float* __restrict__ sm4,
    const int* __restrict__ cnt, const int* __restrict__ wl,
    const float* __restrict__ Wrel, const float* __restrict__ Wroot,
    const float* __restrict__ bias,
    float* __restrict__ onew, float* __restrict__ bnsum, float* __restrict__ bnsq,
    const float* __restrict__ bns0, const float* __restrict__ bnq0,
    const float* __restrict__ g0, const float* __restrict__ b0bn, int fold){
  __shared__ __align__(16) float aggs[8][128];
  __shared__ __align__(16) float xps[8][128];
  __shared__ __align__(16) float scv[128];
  __shared__ __align__(16) float ofv[128];
  const int t = threadIdx.x, grp = t>>5, lane = t&31;
  if(t<128){
    float sv = 1.f, ov = 0.f;
    if(fold){
      float mu = bns0[t]*(1.0f/NN);
      float var = bnq0[t]*(1.0f/NN) - mu*mu;
      sv = g0[t]*rsqrtf(var+1e-5f);
      ov = b0bn[t] - mu*sv;
    }
    scv[t]=sv; ofv[t]=ov;
  }
  __syncthreads();
  const float4 s4l = *(const float4*)&scv[lane*4];
  const float4 o4l = *(const float4*)&ofv[lane*4];
  const int total = *cnt;
  for(int item = blockIdx.x*8 + grp; item < total; item += gridDim.x*8){
    const int wv = wl[item];
    const int h = wv>>16, n = wv & 0xFFFF;
    const float smn = sm4[n*4+h];
    const int e0 = offs[n], e1 = offs[n+1];
    float4 acc = make_float4(-INFINITY,-INFINITY,-INFINITY,-INFINITY);
    bool any = false;
    for(int e=e0;e<e1;e++){
      int s = csr[e];
      if((keep[s]>>h)&1){
        any = true;
        float sv = sm4[s*4+h];
        float4 v = ((const float4*)cur)[s*32 + lane];
        v.x = (v.x*s4l.x + o4l.x)*sv; v.y = (v.y*s4l.y + o4l.y)*sv;
        v.z = (v.z*s4l.z + o4l.z)*sv; v.w = (v.w*s4l.w + o4l.w)*sv;
        acc.x = fmaxf(acc.x, v.x); acc.y = fmaxf(acc.y, v.y);
        acc.z = fmaxf(acc.z, v.z); acc.w = fmaxf(acc.w, v.w);
      }
    }
    if(!any) acc = make_float4(0.f,0.f,0.f,0.f);
    *(float4*)&aggs[grp][lane*4] = acc;
    float4 xv = ((const float4*)cur)[n*32 + lane];
    xv.x = (xv.x*s4l.x + o4l.x)*smn; xv.y = (xv.y*s4l.y + o4l.y)*smn;
    xv.z = (xv.z*s4l.z + o4l.z)*smn; xv.w = (xv.w*s4l.w + o4l.w)*smn;
    *(float4*)&xps[grp][lane*4] = xv;
    // half-wave group: LDS write->read is program-ordered within the wave
    const float* Wr = Wrel  + (size_t)(h*32+lane)*128;
    const float* Wo = Wroot + (size_t)(h*32+lane)*128;
    float o = bias[h*32+lane];
    for(int k=0;k<32;k++){
      float4 a  = *(const float4*)&aggs[grp][k*4];
      float4 xx = *(const float4*)&xps[grp][k*4];
      float4 wr = ((const float4*)Wr)[k];
      float4 wo = ((const float4*)Wo)[k];
      o += a.x*wr.x + a.y*wr.y + a.z*wr.z + a.w*wr.w;
      o += xx.x*wo.x + xx.y*wo.y + xx.z*wo.z + xx.w*wo.w;
    }
    o = lrelu(o);
    onew[(size_t)n*128 + h*32 + lane] = o;
    atomicAdd(&bnsum[h*32+lane], o);
    atomicAdd(&bnsq[h*32+lane], o*o);
  }
}

// ---------- residual update: cur = 0.5*(bn0?(cur)) + 0.25*bn1(new) ----------
__global__ __launch_bounds__(256) void k_update(float* __restrict__ cur,
    const float* __restrict__ onew, const unsigned char* __restrict__ keep,
    const float* __restrict__ bnsum, const float* __restrict__ bnsq,
    const float* __restrict__ gg, const float* __restrict__ bb,
    const float* __restrict__ bns0, const float* __restrict__ bnq0,
    const float* __restrict__ g0, const float* __restrict__ b0bn, int fold){
  __shared__ __align__(16) float sc1[128];
  __shared__ __align__(16) float of1[128];
  __shared__ __align__(16) float sc0[128];
  __shared__ __align__(16) float of0[128];
  int t = threadIdx.x;
  if(t<128){
    float mu = bnsum[t]*(1.0f/NN);
    float var = bnsq[t]*(1.0f/NN) - mu*mu;
    float rs = rsqrtf(var+1e-5f);
    float s = gg[t]*rs;
    sc1[t]=s; of1[t]=bb[t]-mu*s;
    float s0v = 1.f, o0v = 0.f;
    if(fold){
      float mu0 = bns0[t]*(1.0f/NN);
      float var0 = bnq0[t]*(1.0f/NN) - mu0*mu0;
      s0v = g0[t]*rsqrtf(var0+1e-5f);
      o0v = b0bn[t] - mu0*s0v;
    }
    sc0[t]=s0v; of0[t]=o0v;
  }
  __syncthreads();
  int tid = blockIdx.x*256 + t;
  int n = tid>>5, q = tid&31, h = q>>3;
  float4 v = ((const float4*)cur)[tid];
  float4 nv = make_float4(0.f,0.f,0.f,0.f);
  if((keep[n]>>h)&1) nv = ((const float4*)onew)[tid];
  float4 s1 = *(const float4*)&sc1[q*4];
  float4 o1 = *(const float4*)&of1[q*4];
  float4 s0 = *(const float4*)&sc0[q*4];
  float4 o0 = *(const float4*)&of0[q*4];
  v.x = 0.5f*(s0.x*v.x + o0.x) + 0.25f*(s1.x*nv.x + o1.x);
  v.y = 0.5f*(s0.y*v.y + o0.y) + 0.25f*(s1.y*nv.y + o1.y);
  v.z = 0.5f*(s0.z*v.z + o0.z) + 0.25f*(s1.z*nv.z + o1.z);
  v.w = 0.5f*(s0.w*v.w + o0.w) + 0.25f*(s1.w*nv.w + o1.w);
  ((float4*)cur)[tid] = v;
}

// ---------- classification heads ----------
__global__ __launch_bounds__(256) void k_cls(const float* __restrict__ cur,
    const float* __restrict__ pw,
    const float* __restrict__ gW1, const float* __restrict__ gb1,
    const float* __restrict__ gW2, const float* __restrict__ gb2,
    const float* __restrict__ fW1, const float* __restrict__ fb1,
    const float* __restrict__ fW2, const float* __restrict__ fb2,
    float* __restrict__ out){
  __shared__ __align__(16) float w[4][128];
  __shared__ float red[4];
  __shared__ int keptL[256];
  __shared__ float keptS[256];
  __shared__ float gateL[256];
  __shared__ __align__(16) float xk[128];
  __shared__ __align__(16) float pooled[128];
  __shared__ float yv[4];
  __shared__ int nkept;
  const int t = threadIdx.x, g = blockIdx.x;
  for(int i=t;i<512;i+=256) w[i>>7][i&127] = pw[i];
  __syncthreads();
  const int n = g*256 + t;
  const float4* row = (const float4*)(cur + (size_t)n*128);
  float sc4[4]={0.f,0.f,0.f,0.f};
  for(int k=0;k<32;k++){
    float4 v = row[k];
    #pragma unroll
    for(int c=0;c<4;c++){
      const float4 wv = *(const float4*)&w[c][k*4];
      sc4[c] += v.x*wv.x + v.y*wv.y + v.z*wv.z + v.w*wv.w;
    }
  }
  #pragma unroll 1
  for(int c=0;c<4;c++){
    float m = blockMax4(sc4[c], red);
    float e = expf(sc4[c]-m);
    float ssum = blockSum4(e, red);
    float sm = e/(ssum+1e-16f);
    float smax = blockMax4(sm, red);
    float thr = fminf(smax - 1e-7f, 0.8f);
    if(t==0) nkept = 0;
    __syncthreads();
    if(sm > thr){
      int p = atomicAdd(&nkept,1);
      keptL[p]=t; keptS[p]=sm;
    }
    __syncthreads();
    const int K = nkept;
    for(int k=0;k<K;k++){
      int ln = keptL[k]; float sv = keptS[k];
      if(t<32){
        float4 v = ((const float4*)(cur + (size_t)(g*256+ln)*128))[t];
        v.x*=sv; v.y*=sv; v.z*=sv; v.w*=sv;
        *(float4*)&xk[t*4] = v;
      }
      __syncthreads();
      float part = 0.f;
      if(t<128){
        const float* W = gW1 + (size_t)c*16384 + (size_t)t*128;
        float a = gb1[c*128+t];
        for(int f=0;f<32;f++){
          float4 xv = *(const float4*)&xk[f*4];
          float4 wv = ((const float4*)W)[f];
          a += xv.x*wv.x + xv.y*wv.y + xv.z*wv.z + xv.w*wv.w;
        }
        part = lrelu(a) * gW2[c*128+t];
      }
      float gs = blockSum4(part, red);
      if(t==0) gateL[k] = gs + gb2[c];
      __syncthreads();
    }
    float gv = (t<K)? gateL[t] : -INFINITY;
    float gm = blockMax4(gv, red);
    float ge = (t<K)? expf(gv-gm) : 0.f;
    float gsum = blockSum4(ge, red);
    if(t<K) gateL[t] = ge/(gsum+1e-16f);
    __syncthreads();
    if(t<128){
      float acc = 0.f;
      for(int k=0;k<K;k++)
        acc += gateL[k]*keptS[k]*cur[(size_t)(g*256+keptL[k])*128 + t];
      pooled[t]=acc;
    }
    __syncthreads();
    float part2=0.f;
    if(t<128){
      const float* F = fW1 + (size_t)c*16384 + (size_t)t*128;
      float a = fb1[c*128+t];
      for(int f=0;f<32;f++){
        float4 xv = *(const float4*)&pooled[f*4];
        float4 wv = ((const float4*)F)[f];
        a += xv.x*wv.x + xv.y*wv.y + xv.z*wv.z + xv.w*wv.w;
      }
      part2 = lrelu(a) * fW2[c*128+t];
    }
    float ysum = blockSum4(part2, red);
    if(t==0) yv[c] = ysum + fb2[c];
    __syncthreads();
  }
  if(t<4){
    float m = fmaxf(fmaxf(yv[0],yv[1]), fmaxf(yv[2],yv[3]));
    float l = logf(expf(yv[0]-m)+expf(yv[1]-m)+expf(yv[2]-m)+expf(yv[3]-m));
    out[g*4+t] = yv[t] - m - l;
  }
}

extern "C" void kernel_launch(void* const* d_in, const int* in_sizes, int n_in,
                              void* d_out, int out_size, void* d_ws, size_t ws_size,
                              hipStream_t stream){
  (void)in_sizes; (void)n_in; (void)out_size; (void)ws_size;
  const float* x     = (const float*)d_in[0];
  const int*   ei    = (const int*)d_in[1];
  const float* Wrel0 = (const float*)d_in[3];
  const float* Wroot0= (const float*)d_in[4];
  const float* b0    = (const float*)d_in[5];
  const float* bn0g  = (const float*)d_in[6];
  const float* bn0b  = (const float*)d_in[7];
  const float* bpw   = (const float*)d_in[8];
  const float* bWrel = (const float*)d_in[9];
  const float* bWroot= (const float*)d_in[10];
  const float* bbv   = (const float*)d_in[11];
  const float* bbng  = (const float*)d_in[12];
  const float* bbnb  = (const float*)d_in[13];
  const float* cpw   = (const float*)d_in[14];
  const float* gW1   = (const float*)d_in[15];
  const float* gb1   = (const float*)d_in[16];
  const float* gW2   = (const float*)d_in[17];
  const float* gb2   = (const float*)d_in[18];
  const float* fW1   = (const float*)d_in[19];
  const float* fb1   = (const float*)d_in[20];
  const float* fW2   = (const float*)d_in[21];
  const float* fb2   = (const float*)d_in[22];

  char* ws = (char*)d_ws;
  float* cur   = (float*)(ws + 0);                 // 33.55 MB
  float* onew  = (float*)(ws + 33554432ull);       // 33.55 MB (agg0 aliases first 16.8 MB)
  float* agg0  = onew;
  int*   csr   = (int*)(ws + 67108864ull);         // 2 MB
  float* sm4   = (float*)(ws + 69206016ull);       // 1 MB
  int*   wl    = (int*)(ws + 70254592ull);         // 1 MB
  int*   offs  = (int*)(ws + 71303168ull);         // 256 KB + pad
  int*   cursor= (int*)(ws + 71565568ull);         // 256 KB
  unsigned char* keep = (unsigned char*)(ws + 71827712ull); // 64 KB
  char*  Z     = ws + 71893248ull;                 // zero-init region
  int*   deg   = (int*)Z;
  float* bnsum0= (float*)(Z + 262144);
  float* bnsq0 = (float*)(Z + 262656);
  float* bnA   = (float*)(Z + 263168);
  float* bqA   = (float*)(Z + 263680);
  float* bnB   = (float*)(Z + 264192);
  float* bqB   = (float*)(Z + 264704);
  int*   cnt0  = (int*)(Z + 265216);
  int*   cnt1  = (int*)(Z + 265220);

  hipMemsetAsync(Z, 0, 265224, stream);

  // CSR by dst
  k_count  <<<2048,256,0,stream>>>(ei, deg);
  k_scan   <<<1,1024,0,stream>>>(deg, offs, cursor);
  k_scatter<<<2048,256,0,stream>>>(ei, cursor, csr);

  // conv0 -> lrelu (bn0 kept folded: stats only, apply deferred to consumers)
  k_agg0    <<<4096,256,0,stream>>>(x, offs, csr, agg0);
  k_conv0mm <<<1024,256,0,stream>>>(agg0, x, Wrel0, Wroot0, b0, cur);
  k_bnstats <<<256,256,0,stream>>>(cur, bnsum0, bnsq0);

  // block layer 0 (bn0 folded into pool/blockconv/update)
  k_pool     <<<256,256,0,stream>>>(cur, bpw, 0.7f, sm4, keep, cnt0, wl,
                                    bnsum0, bnsq0, bn0g, 1);
  k_blockconv<<<256,256,0,stream>>>(cur, offs, csr, keep, sm4, cnt0, wl,
                                    bWrel, bWroot, bbv, onew, bnA, bqA,
                                    bnsum0, bnsq0, bn0g, bn0b, 1);
  k_update   <<<8192,256,0,stream>>>(cur, onew, keep, bnA, bqA, bbng, bbnb,
                                    bnsum0, bnsq0, bn0g, bn0b, 1);

  // block layer 1 (cur fully materialized; no fold)
  k_pool     <<<256,256,0,stream>>>(cur, bpw + 512, 0.7f, sm4, keep, cnt1, wl,
                                    bnsum0, bnsq0, bn0g, 0);
  k_blockconv<<<256,256,0,stream>>>(cur, offs, csr, keep, sm4, cnt1, wl,
                                    bWrel + 16384, bWroot + 16384, bbv + 128, onew, bnB, bqB,
                                    bnsum0, bnsq0, bn0g, bn0b, 0);
  k_update   <<<8192,256,0,stream>>>(cur, onew, keep, bnB, bqB, bbng + 128, bbnb + 128,
                                    bnsum0, bnsq0, bn0g, bn0b, 0);

  // classification heads + log_softmax
  k_cls<<<256,256,0,stream>>>(cur, cpw, gW1, gb1, gW2, gb2, fW1, fb1, fW2, fb2,
                              (float*)d_out);
}

// Round 3
// 443.541 us; speedup vs baseline: 1.6387x; 1.2139x over previous
//
#include <hip/hip_runtime.h>
#include <math.h>

#define NN 65536      // nodes
#define NE 524288     // edges
#define NG 256        // graphs (256 contiguous nodes each)
#define SLOPE 0.01f

__device__ __forceinline__ float lrelu(float v){ return v > 0.f ? v : SLOPE*v; }

// ---------- block reductions (256-thread blocks = 4 waves) ----------
__device__ __forceinline__ float blockMax4(float v, float* s4){
  #pragma unroll
  for(int o=32;o>0;o>>=1) v = fmaxf(v, __shfl_down(v, o, 64));
  int t = threadIdx.x;
  __syncthreads();
  if((t&63)==0) s4[t>>6] = v;
  __syncthreads();
  return fmaxf(fmaxf(s4[0], s4[1]), fmaxf(s4[2], s4[3]));
}
__device__ __forceinline__ float blockSum4(float v, float* s4){
  #pragma unroll
  for(int o=32;o>0;o>>=1) v += __shfl_down(v, o, 64);
  int t = threadIdx.x;
  __syncthreads();
  if((t&63)==0) s4[t>>6] = v;
  __syncthreads();
  return (s4[0]+s4[1])+(s4[2]+s4[3]);
}

// ---------- CSR build (by dst) ----------
__global__ __launch_bounds__(256) void k_count(const int* __restrict__ ei, int* __restrict__ deg){
  int e = blockIdx.x*256 + threadIdx.x;
  if(e < NE) atomicAdd(&deg[ei[NE + e]], 1);
}

__global__ __launch_bounds__(1024) void k_scan(const int* __restrict__ deg,
      int* __restrict__ offs, int* __restrict__ cursor){
  __shared__ int part[1024];
  int t = threadIdx.x;
  int base = t*64;
  int s=0;
  for(int i=0;i<64;i++) s += deg[base+i];
  part[t]=s;
  __syncthreads();
  for(int off=1; off<1024; off<<=1){
    int v = (t>=off)? part[t-off] : 0;
    __syncthreads();
    part[t] += v;
    __syncthreads();
  }
  int run = (t==0)? 0 : part[t-1];
  for(int i=0;i<64;i++){
    int d = deg[base+i];
    offs[base+i] = run; cursor[base+i] = run;
    run += d;
  }
  if(t==1023) offs[NN] = run;
}

__global__ __launch_bounds__(256) void k_scatter(const int* __restrict__ ei,
      int* __restrict__ cursor, int* __restrict__ csr){
  int e = blockIdx.x*256 + threadIdx.x;
  if(e < NE){
    int d = ei[NE + e];
    int p = atomicAdd(&cursor[d], 1);
    csr[p] = ei[e];
  }
}

// ---------- conv0: agg[i] = max over in-edges of x[src], else 0 ----------
__global__ __launch_bounds__(256) void k_agg0(const float* __restrict__ x,
    const int* __restrict__ offs, const int* __restrict__ csr, float* __restrict__ agg0){
  int tid = blockIdx.x*256 + threadIdx.x;
  int node = tid>>4, q = tid&15;        // 16 threads (float4 lanes) per node
  int e0 = offs[node], e1 = offs[node+1];
  float4 acc = make_float4(0.f,0.f,0.f,0.f);
  if(e0 < e1){
    acc = make_float4(-INFINITY,-INFINITY,-INFINITY,-INFINITY);
    int e = e0;
    for(; e+3 < e1; e += 4){            // 4-edge unroll: 4 independent gathers in flight
      int s0 = csr[e], s1 = csr[e+1], s2 = csr[e+2], s3 = csr[e+3];
      float4 v0 = ((const float4*)x)[s0*16 + q];
      float4 v1 = ((const float4*)x)[s1*16 + q];
      float4 v2 = ((const float4*)x)[s2*16 + q];
      float4 v3 = ((const float4*)x)[s3*16 + q];
      acc.x=fmaxf(acc.x,fmaxf(fmaxf(v0.x,v1.x),fmaxf(v2.x,v3.x)));
      acc.y=fmaxf(acc.y,fmaxf(fmaxf(v0.y,v1.y),fmaxf(v2.y,v3.y)));
      acc.z=fmaxf(acc.z,fmaxf(fmaxf(v0.z,v1.z),fmaxf(v2.z,v3.z)));
      acc.w=fmaxf(acc.w,fmaxf(fmaxf(v0.w,v1.w),fmaxf(v2.w,v3.w)));
    }
    for(; e < e1; e++){
      int s0 = csr[e];
      float4 v0 = ((const float4*)x)[s0*16 + q];
      acc.x=fmaxf(acc.x,v0.x); acc.y=fmaxf(acc.y,v0.y);
      acc.z=fmaxf(acc.z,v0.z); acc.w=fmaxf(acc.w,v0.w);
    }
  }
  ((float4*)agg0)[node*16 + q] = acc;
}

// ---------- conv0 matmul: cur = lrelu([agg0|x] @ [Wrel|Wroot]^T + b0) ----------
// 128x128 tile, 8x8 microtile, K chunked 64 (chunk0 = agg0/Wrel, chunk1 = x/Wroot
// — both chunks are contiguous 32KB copies). float4 XOR-swizzled LDS:
// element (n,k4) at n*16 + ((k4 + (n>>3))&15). A compute-reads are 2-way bank
// aliased (free, m136); W reads are 16-lane broadcasts. bn0 stats fused in epilogue.
__global__ __launch_bounds__(256, 2) void k_conv0mm(
    const float* __restrict__ agg0, const float* __restrict__ x,
    const float* __restrict__ Wrel, const float* __restrict__ Wroot,
    const float* __restrict__ b0, float* __restrict__ cur,
    float* __restrict__ bnsum, float* __restrict__ bnsq){
  __shared__ float4 As[2048];   // 32 KB
  __shared__ float4 Ws[2048];   // 32 KB
  const int t = threadIdx.x;
  const int tn = t & 15;        // node group: nodes tn*8..tn*8+7
  const int tc = t >> 4;        // col group:  cols  tc*8..tc*8+7
  float acc[8][8];
  #pragma unroll
  for(int i=0;i<8;i++)
    #pragma unroll
    for(int j=0;j<8;j++) acc[i][j]=0.f;

  const size_t tileoff = (size_t)blockIdx.x * 8192;   // 128 nodes * 64 floats
  #pragma unroll 1
  for(int ch=0; ch<2; ch++){
    const float4* gA = (const float4*)((ch==0? agg0 : x) + tileoff);
    const float4* gW = (const float4*)(ch==0? Wrel : Wroot);
    __syncthreads();
    #pragma unroll
    for(int i=0;i<8;i++){
      int idx = t + i*256;
      int n = idx>>4, k4 = idx&15;
      int sw = n*16 + ((k4 + (n>>3))&15);
      As[sw] = gA[idx];
      Ws[sw] = gW[idx];
    }
    __syncthreads();
    #pragma unroll 4
    for(int k4=0;k4<16;k4++){
      float4 a4[8], w4[8];
      #pragma unroll
      for(int i=0;i<8;i++) a4[i] = As[(tn*8+i)*16 + ((k4+tn)&15)];
      #pragma unroll
      for(int i=0;i<8;i++) w4[i] = Ws[(tc*8+i)*16 + ((k4+tc)&15)];
      #pragma unroll
      for(int i=0;i<8;i++)
        #pragma unroll
        for(int j=0;j<8;j++){
          acc[i][j] = fmaf(a4[i].x, w4[j].x, acc[i][j]);
          acc[i][j] = fmaf(a4[i].y, w4[j].y, acc[i][j]);
          acc[i][j] = fmaf(a4[i].z, w4[j].z, acc[i][j]);
          acc[i][j] = fmaf(a4[i].w, w4[j].w, acc[i][j]);
        }
    }
  }

  // epilogue: bias + lrelu + store + fused bn-stat partials
  float bj[8];
  #pragma unroll
  for(int j=0;j<8;j++) bj[j] = b0[tc*8+j];
  float cs[8], cq[8];
  #pragma unroll
  for(int j=0;j<8;j++){ cs[j]=0.f; cq[j]=0.f; }
  const int nbase = blockIdx.x*128;
  #pragma unroll
  for(int i=0;i<8;i++){
    int node = nbase + tn*8 + i;
    float v[8];
    #pragma unroll
    for(int j=0;j<8;j++){
      v[j] = lrelu(acc[i][j] + bj[j]);
      cs[j] += v[j]; cq[j] += v[j]*v[j];
    }
    float4 o0 = make_float4(v[0],v[1],v[2],v[3]);
    float4 o1 = make_float4(v[4],v[5],v[6],v[7]);
    ((float4*)cur)[node*32 + tc*2 + 0] = o0;
    ((float4*)cur)[node*32 + tc*2 + 1] = o1;
  }
  __syncthreads();
  float* reds = (float*)As;   // 128 cols x 16 tn
  float* redq = (float*)Ws;
  #pragma unroll
  for(int j=0;j<8;j++){
    reds[(tc*8+j)*16 + tn] = cs[j];
    redq[(tc*8+j)*16 + tn] = cq[j];
  }
  __syncthreads();
  if(t<128){
    float S=0.f, Q=0.f;
    #pragma unroll
    for(int i=0;i<16;i++){ S += reds[t*16+i]; Q += redq[t*16+i]; }
    atomicAdd(&bnsum[t], S);
    atomicAdd(&bnsq[t], Q);
  }
}

// ---------- TopK pool (layer 0): 4 heads, bn0 scale folded into weights
// (per-graph-constant offset cancels in softmax) ----------
__global__ __launch_bounds__(256) void k_pool(const float* __restrict__ cur,
    const float* __restrict__ pw, float minscore,
    float* __restrict__ sm4, unsigned char* __restrict__ keep,
    int* __restrict__ cnt, int* __restrict__ wl,
    const float* __restrict__ bnsum, const float* __restrict__ bnsq,
    const float* __restrict__ gg, int fold){
  __shared__ __align__(16) float w[4][128];
  __shared__ float red[4];
  __shared__ float scv[128];
  int t = threadIdx.x, g = blockIdx.x;
  if(t<128){
    float sv = 1.f;
    if(fold){
      float mu = bnsum[t]*(1.0f/NN);
      float var = bnsq[t]*(1.0f/NN) - mu*mu;
      sv = gg[t]*rsqrtf(var+1e-5f);
    }
    scv[t] = sv;
  }
  __syncthreads();
  for(int i=t;i<512;i+=256) w[i>>7][i&127] = pw[i]*scv[i&127];
  __syncthreads();
  int n = g*256 + t;
  const float4* row = (const float4*)(cur + (size_t)n*128);
  float sc[4] = {0.f,0.f,0.f,0.f};
  for(int k=0;k<32;k++){
    float4 v = row[k];
    #pragma unroll
    for(int h=0;h<4;h++){
      const float4 wv = *(const float4*)&w[h][k*4];
      sc[h] += v.x*wv.x + v.y*wv.y + v.z*wv.z + v.w*wv.w;
    }
  }
  float4 smout;
  unsigned kb = 0;
  #pragma unroll 1
  for(int h=0;h<4;h++){
    float m = blockMax4(sc[h], red);
    float e = expf(sc[h]-m);
    float ssum = blockSum4(e, red);
    float sm = e/(ssum + 1e-16f);
    float smax = blockMax4(sm, red);
    float thr = fminf(smax - 1e-7f, minscore);
    ((float*)&smout)[h] = sm;
    if(sm > thr){
      kb |= (1u<<h);
      int p = atomicAdd(cnt, 1);
      wl[p] = (h<<16) | n;
    }
  }
  ((float4*)sm4)[n] = smout;
  keep[n] = (unsigned char)kb;
}

// ---------- block-layer GraphConv(max) on kept (head,node) items ----------
__global__ __launch_bounds__(256) void k_blockconv(const float* __restrict__ cur,
    const int* __restrict__ offs, const int* __restrict__ csr,
    const unsigned char* __restrict__ keep, const float* __restrict__ sm4,
    const int* __restrict__ cnt, const int* __restrict__ wl,
    const float* __restrict__ Wrel, const float* __restrict__ Wroot,
    const float* __restrict__ bias,
    float* __restrict__ onew, float* __restrict__ bnsum, float* __restrict__ bnsq,
    const float* __restrict__ bns0, const float* __restrict__ bnq0,
    const float* __restrict__ g0, const float* __restrict__ b0bn, int fold){
  __shared__ __align__(16) float aggs[8][128];
  __shared__ __align__(16) float xps[8][128];
  __shared__ __align__(16) float scv[128];
  __shared__ __align__(16) float ofv[128];
  const int t = threadIdx.x, grp = t>>5, lane = t&31;
  if(t<128){
    float sv = 1.f, ov = 0.f;
    if(fold){
      float mu = bns0[t]*(1.0f/NN);
      float var = bnq0[t]*(1.0f/NN) - mu*mu;
      sv = g0[t]*rsqrtf(var+1e-5f);
      ov = b0bn[t] - mu*sv;
    }
    scv[t]=sv; ofv[t]=ov;
  }
  __syncthreads();
  const float4 s4l = *(const float4*)&scv[lane*4];
  const float4 o4l = *(const float4*)&ofv[lane*4];
  const int total = *cnt;
  for(int item = blockIdx.x*8 + grp; item < total; item += gridDim.x*8){
    const int wv = wl[item];
    const int h = wv>>16, n = wv & 0xFFFF;
    const float smn = sm4[n*4+h];
    const int e0 = offs[n], e1 = offs[n+1];
    float4 acc = make_float4(-INFINITY,-INFINITY,-INFINITY,-INFINITY);
    bool any = false;
    for(int e=e0;e<e1;e++){
      int s = csr[e];
      if((keep[s]>>h)&1){
        any = true;
        float sv = sm4[s*4+h];
        float4 v = ((const float4*)cur)[s*32 + lane];
        v.x = (v.x*s4l.x + o4l.x)*sv; v.y = (v.y*s4l.y + o4l.y)*sv;
        v.z = (v.z*s4l.z + o4l.z)*sv; v.w = (v.w*s4l.w + o4l.w)*sv;
        acc.x = fmaxf(acc.x, v.x); acc.y = fmaxf(acc.y, v.y);
        acc.z = fmaxf(acc.z, v.z); acc.w = fmaxf(acc.w, v.w);
      }
    }
    if(!any) acc = make_float4(0.f,0.f,0.f,0.f);
    *(float4*)&aggs[grp][lane*4] = acc;
    float4 xv = ((const float4*)cur)[n*32 + lane];
    xv.x = (xv.x*s4l.x + o4l.x)*smn; xv.y = (xv.y*s4l.y + o4l.y)*smn;
    xv.z = (xv.z*s4l.z + o4l.z)*smn; xv.w = (xv.w*s4l.w + o4l.w)*smn;
    *(float4*)&xps[grp][lane*4] = xv;
    // half-wave group: LDS write->read is program-ordered within the wave
    const float* Wr = Wrel  + (size_t)(h*32+lane)*128;
    const float* Wo = Wroot + (size_t)(h*32+lane)*128;
    float o = bias[h*32+lane];
    for(int k=0;k<32;k++){
      float4 a  = *(const float4*)&aggs[grp][k*4];
      float4 xx = *(const float4*)&xps[grp][k*4];
      float4 wr = ((const float4*)Wr)[k];
      float4 wo = ((const float4*)Wo)[k];
      o += a.x*wr.x + a.y*wr.y + a.z*wr.z + a.w*wr.w;
      o += xx.x*wo.x + xx.y*wo.y + xx.z*wo.z + xx.w*wo.w;
    }
    o = lrelu(o);
    onew[(size_t)n*128 + h*32 + lane] = o;
    atomicAdd(&bnsum[h*32+lane], o);
    atomicAdd(&bnsq[h*32+lane], o*o);
  }
}

// ---------- fused: residual update (layer0, bn0-folded) + TopK pool (layer1) ----------
__global__ __launch_bounds__(256) void k_updatepool(float* __restrict__ cur,
    const float* __restrict__ onew, const unsigned char* __restrict__ keepin,
    const float* __restrict__ bnsum, const float* __restrict__ bnsq,
    const float* __restrict__ gg, const float* __restrict__ bb,
    const float* __restrict__ bns0, const float* __restrict__ bnq0,
    const float* __restrict__ g0, const float* __restrict__ b0bn,
    const float* __restrict__ pw, float minscore,
    float* __restrict__ sm4, unsigned char* __restrict__ keepout,
    int* __restrict__ cnt, int* __restrict__ wl){
  __shared__ __align__(16) float sc1[128], of1[128], sc0[128], of0[128];
  __shared__ __align__(16) float w[4][128];
  __shared__ float red[4];
  const int t = threadIdx.x, g = blockIdx.x;
  if(t<128){
    float mu = bnsum[t]*(1.0f/NN);
    float var = bnsq[t]*(1.0f/NN) - mu*mu;
    float s = gg[t]*rsqrtf(var+1e-5f);
    sc1[t]=s; of1[t]=bb[t]-mu*s;
    float mu0 = bns0[t]*(1.0f/NN);
    float var0 = bnq0[t]*(1.0f/NN) - mu0*mu0;
    float s0v = g0[t]*rsqrtf(var0+1e-5f);
    sc0[t]=s0v; of0[t]=b0bn[t]-mu0*s0v;
  }
  for(int i=t;i<512;i+=256) w[i>>7][i&127] = pw[i];
  __syncthreads();
  const int n = g*256 + t;
  const unsigned kb_in = keepin[n];
  float sc[4] = {0.f,0.f,0.f,0.f};
  for(int k=0;k<32;k++){
    int h = k>>3;
    float4 v = ((const float4*)cur)[n*32 + k];
    float4 nv = make_float4(0.f,0.f,0.f,0.f);
    if((kb_in>>h)&1) nv = ((const float4*)onew)[n*32 + k];
    float4 s1 = *(const float4*)&sc1[k*4];
    float4 o1 = *(const float4*)&of1[k*4];
    float4 s0 = *(const float4*)&sc0[k*4];
    float4 o0 = *(const float4*)&of0[k*4];
    v.x = 0.5f*(s0.x*v.x + o0.x) + 0.25f*(s1.x*nv.x + o1.x);
    v.y = 0.5f*(s0.y*v.y + o0.y) + 0.25f*(s1.y*nv.y + o1.y);
    v.z = 0.5f*(s0.z*v.z + o0.z) + 0.25f*(s1.z*nv.z + o1.z);
    v.w = 0.5f*(s0.w*v.w + o0.w) + 0.25f*(s1.w*nv.w + o1.w);
    ((float4*)cur)[n*32 + k] = v;
    #pragma unroll
    for(int h2=0;h2<4;h2++){
      const float4 wv = *(const float4*)&w[h2][k*4];
      sc[h2] += v.x*wv.x + v.y*wv.y + v.z*wv.z + v.w*wv.w;
    }
  }
  float4 smout;
  unsigned kb = 0;
  #pragma unroll 1
  for(int h=0;h<4;h++){
    float m = blockMax4(sc[h], red);
    float e = expf(sc[h]-m);
    float ssum = blockSum4(e, red);
    float sm = e/(ssum + 1e-16f);
    float smax = blockMax4(sm, red);
    float thr = fminf(smax - 1e-7f, minscore);
    ((float*)&smout)[h] = sm;
    if(sm > thr){
      kb |= (1u<<h);
      int p = atomicAdd(cnt, 1);
      wl[p] = (h<<16) | n;
    }
  }
  ((float4*)sm4)[n] = smout;
  keepout[n] = (unsigned char)kb;
}

// ---------- fused: residual update (layer1) + classification heads ----------
__global__ __launch_bounds__(256) void k_updatecls(float* __restrict__ cur,
    const float* __restrict__ onew, const unsigned char* __restrict__ keepin,
    const float* __restrict__ bnsum, const float* __restrict__ bnsq,
    const float* __restrict__ gg, const float* __restrict__ bb,
    const float* __restrict__ pw,
    const float* __restrict__ gW1, const float* __restrict__ gb1,
    const float* __restrict__ gW2, const float* __restrict__ gb2,
    const float* __restrict__ fW1, const float* __restrict__ fb1,
    const float* __restrict__ fW2, const float* __restrict__ fb2,
    float* __restrict__ out){
  __shared__ __align__(16) float sc1[128], of1[128];
  __shared__ __align__(16) float w[4][128];
  __shared__ float red[4];
  __shared__ int keptL[256];
  __shared__ float keptS[256];
  __shared__ float gateL[256];
  __shared__ __align__(16) float xk[128];
  __shared__ __align__(16) float pooled[128];
  __shared__ float yv[4];
  __shared__ int nkept;
  const int t = threadIdx.x, g = blockIdx.x;
  if(t<128){
    float mu = bnsum[t]*(1.0f/NN);
    float var = bnsq[t]*(1.0f/NN) - mu*mu;
    float s = gg[t]*rsqrtf(var+1e-5f);
    sc1[t]=s; of1[t]=bb[t]-mu*s;
  }
  for(int i=t;i<512;i+=256) w[i>>7][i&127] = pw[i];
  __syncthreads();
  const int n = g*256 + t;
  const unsigned kb_in = keepin[n];
  float sc4[4] = {0.f,0.f,0.f,0.f};
  for(int k=0;k<32;k++){
    int h = k>>3;
    float4 v = ((const float4*)cur)[n*32 + k];
    float4 nv = make_float4(0.f,0.f,0.f,0.f);
    if((kb_in>>h)&1) nv = ((const float4*)onew)[n*32 + k];
    float4 s1 = *(const float4*)&sc1[k*4];
    float4 o1 = *(const float4*)&of1[k*4];
    v.x = 0.5f*v.x + 0.25f*(s1.x*nv.x + o1.x);
    v.y = 0.5f*v.y + 0.25f*(s1.y*nv.y + o1.y);
    v.z = 0.5f*v.z + 0.25f*(s1.z*nv.z + o1.z);
    v.w = 0.5f*v.w + 0.25f*(s1.w*nv.w + o1.w);
    ((float4*)cur)[n*32 + k] = v;
    #pragma unroll
    for(int c=0;c<4;c++){
      const float4 wv = *(const float4*)&w[c][k*4];
      sc4[c] += v.x*wv.x + v.y*wv.y + v.z*wv.z + v.w*wv.w;
    }
  }
  __syncthreads();   // block-scope fence: updated cur rows visible to whole block
  #pragma unroll 1
  for(int c=0;c<4;c++){
    float m = blockMax4(sc4[c], red);
    float e = expf(sc4[c]-m);
    float ssum = blockSum4(e, red);
    float sm = e/(ssum+1e-16f);
    float smax = blockMax4(sm, red);
    float thr = fminf(smax - 1e-7f, 0.8f);
    if(t==0) nkept = 0;
    __syncthreads();
    if(sm > thr){
      int p = atomicAdd(&nkept,1);
      keptL[p]=t; keptS[p]=sm;
    }
    __syncthreads();
    const int K = nkept;
    for(int k=0;k<K;k++){
      int ln = keptL[k]; float sv = keptS[k];
      if(t<32){
        float4 v = ((const float4*)(cur + (size_t)(g*256+ln)*128))[t];
        v.x*=sv; v.y*=sv; v.z*=sv; v.w*=sv;
        *(float4*)&xk[t*4] = v;
      }
      __syncthreads();
      float part = 0.f;
      if(t<128){
        const float* W = gW1 + (size_t)c*16384 + (size_t)t*128;
        float a = gb1[c*128+t];
        for(int f=0;f<32;f++){
          float4 xv = *(const float4*)&xk[f*4];
          float4 wv = ((const float4*)W)[f];
          a += xv.x*wv.x + xv.y*wv.y + xv.z*wv.z + xv.w*wv.w;
        }
        part = lrelu(a) * gW2[c*128+t];
      }
      float gs = blockSum4(part, red);
      if(t==0) gateL[k] = gs + gb2[c];
      __syncthreads();
    }
    float gv = (t<K)? gateL[t] : -INFINITY;
    float gm = blockMax4(gv, red);
    float ge = (t<K)? expf(gv-gm) : 0.f;
    float gsum = blockSum4(ge, red);
    if(t<K) gateL[t] = ge/(gsum+1e-16f);
    __syncthreads();
    if(t<128){
      float acc = 0.f;
      for(int k=0;k<K;k++)
        acc += gateL[k]*keptS[k]*cur[(size_t)(g*256+keptL[k])*128 + t];
      pooled[t]=acc;
    }
    __syncthreads();
    float part2=0.f;
    if(t<128){
      const float* F = fW1 + (size_t)c*16384 + (size_t)t*128;
      float a = fb1[c*128+t];
      for(int f=0;f<32;f++){
        float4 xv = *(const float4*)&pooled[f*4];
        float4 wv = ((const float4*)F)[f];
        a += xv.x*wv.x + xv.y*wv.y + xv.z*wv.z + xv.w*wv.w;
      }
      part2 = lrelu(a) * fW2[c*128+t];
    }
    float ysum = blockSum4(part2, red);
    if(t==0) yv[c] = ysum + fb2[c];
    __syncthreads();
  }
  if(t<4){
    float m = fmaxf(fmaxf(yv[0],yv[1]), fmaxf(yv[2],yv[3]));
    float l = logf(expf(yv[0]-m)+expf(yv[1]-m)+expf(yv[2]-m)+expf(yv[3]-m));
    out[g*4+t] = yv[t] - m - l;
  }
}

extern "C" void kernel_launch(void* const* d_in, const int* in_sizes, int n_in,
                              void* d_out, int out_size, void* d_ws, size_t ws_size,
                              hipStream_t stream){
  (void)in_sizes; (void)n_in; (void)out_size; (void)ws_size;
  const float* x     = (const float*)d_in[0];
  const int*   ei    = (const int*)d_in[1];
  const float* Wrel0 = (const float*)d_in[3];
  const float* Wroot0= (const float*)d_in[4];
  const float* b0    = (const float*)d_in[5];
  const float* bn0g  = (const float*)d_in[6];
  const float* bn0b  = (const float*)d_in[7];
  const float* bpw   = (const float*)d_in[8];
  const float* bWrel = (const float*)d_in[9];
  const float* bWroot= (const float*)d_in[10];
  const float* bbv   = (const float*)d_in[11];
  const float* bbng  = (const float*)d_in[12];
  const float* bbnb  = (const float*)d_in[13];
  const float* cpw   = (const float*)d_in[14];
  const float* gW1   = (const float*)d_in[15];
  const float* gb1   = (const float*)d_in[16];
  const float* gW2   = (const float*)d_in[17];
  const float* gb2   = (const float*)d_in[18];
  const float* fW1   = (const float*)d_in[19];
  const float* fb1   = (const float*)d_in[20];
  const float* fW2   = (const float*)d_in[21];
  const float* fb2   = (const float*)d_in[22];

  char* ws = (char*)d_ws;
  float* cur   = (float*)(ws + 0);                 // 33.55 MB
  float* onew  = (float*)(ws + 33554432ull);       // 33.55 MB (agg0 aliases first 16.8 MB)
  float* agg0  = onew;
  int*   csr   = (int*)(ws + 67108864ull);         // 2 MB
  float* sm4   = (float*)(ws + 69206016ull);       // 1 MB
  int*   wl    = (int*)(ws + 70254592ull);         // 1 MB
  int*   offs  = (int*)(ws + 71303168ull);         // 256 KB + pad
  int*   cursor= (int*)(ws + 71565568ull);         // 256 KB
  unsigned char* keep = (unsigned char*)(ws + 71827712ull); // 64 KB
  char*  Z     = ws + 71893248ull;                 // zero-init region
  int*   deg   = (int*)Z;
  float* bnsum0= (float*)(Z + 262144);
  float* bnsq0 = (float*)(Z + 262656);
  float* bnA   = (float*)(Z + 263168);
  float* bqA   = (float*)(Z + 263680);
  float* bnB   = (float*)(Z + 264192);
  float* bqB   = (float*)(Z + 264704);
  int*   cnt0  = (int*)(Z + 265216);
  int*   cnt1  = (int*)(Z + 265220);

  hipMemsetAsync(Z, 0, 265224, stream);

  // CSR by dst
  k_count  <<<2048,256,0,stream>>>(ei, deg);
  k_scan   <<<1,1024,0,stream>>>(deg, offs, cursor);
  k_scatter<<<2048,256,0,stream>>>(ei, cursor, csr);

  // conv0 -> lrelu (+ fused bn0 stats; bn0 apply stays folded into consumers)
  k_agg0    <<<4096,256,0,stream>>>(x, offs, csr, agg0);
  k_conv0mm <<<512,256,0,stream>>>(agg0, x, Wrel0, Wroot0, b0, cur, bnsum0, bnsq0);

  // block layer 0 (bn0 folded into pool/blockconv; update folds bn0 too)
  k_pool     <<<256,256,0,stream>>>(cur, bpw, 0.7f, sm4, keep, cnt0, wl,
                                    bnsum0, bnsq0, bn0g, 1);
  k_blockconv<<<256,256,0,stream>>>(cur, offs, csr, keep, sm4, cnt0, wl,
                                    bWrel, bWroot, bbv, onew, bnA, bqA,
                                    bnsum0, bnsq0, bn0g, bn0b, 1);

  // fused: update layer0 (materializes cur) + pool layer1
  k_updatepool<<<256,256,0,stream>>>(cur, onew, keep, bnA, bqA, bbng, bbnb,
                                     bnsum0, bnsq0, bn0g, bn0b,
                                     bpw + 512, 0.7f, sm4, keep, cnt1, wl);

  // block layer 1 (cur materialized; no fold)
  k_blockconv<<<256,256,0,stream>>>(cur, offs, csr, keep, sm4, cnt1, wl,
                                    bWrel + 16384, bWroot + 16384, bbv + 128, onew, bnB, bqB,
                                    bnsum0, bnsq0, bn0g, bn0b, 0);

  // fused: update layer1 + classification heads + log_softmax
  k_updatecls<<<256,256,0,stream>>>(cur, onew, keep, bnB, bqB, bbng + 128, bbnb + 128,
                                    cpw, gW1, gb1, gW2, gb2, fW1, fb1, fW2, fb2,
                                    (float*)d_out);
}

// Round 4
// 422.094 us; speedup vs baseline: 1.7220x; 1.0508x over previous
//
#include <hip/hip_runtime.h>
#include <math.h>

#define NN 65536      // nodes
#define NE 524288     // edges
#define NG 256        // graphs (256 contiguous nodes each)
#define SLOPE 0.01f

__device__ __forceinline__ float lrelu(float v){ return v > 0.f ? v : SLOPE*v; }

// ---------- block reductions (256-thread blocks = 4 waves) ----------
__device__ __forceinline__ float blockMax4(float v, float* s4){
  #pragma unroll
  for(int o=32;o>0;o>>=1) v = fmaxf(v, __shfl_down(v, o, 64));
  int t = threadIdx.x;
  __syncthreads();
  if((t&63)==0) s4[t>>6] = v;
  __syncthreads();
  return fmaxf(fmaxf(s4[0], s4[1]), fmaxf(s4[2], s4[3]));
}
__device__ __forceinline__ float blockSum4(float v, float* s4){
  #pragma unroll
  for(int o=32;o>0;o>>=1) v += __shfl_down(v, o, 64);
  int t = threadIdx.x;
  __syncthreads();
  if((t&63)==0) s4[t>>6] = v;
  __syncthreads();
  return (s4[0]+s4[1])+(s4[2]+s4[3]);
}

// ---------- CSR build (by dst) ----------
__global__ __launch_bounds__(256) void k_count(const int* __restrict__ ei, int* __restrict__ deg){
  int e = blockIdx.x*256 + threadIdx.x;
  if(e < NE) atomicAdd(&deg[ei[NE + e]], 1);
}

__global__ __launch_bounds__(1024) void k_scan(const int* __restrict__ deg,
      int* __restrict__ offs, int* __restrict__ cursor){
  __shared__ int part[1024];
  int t = threadIdx.x;
  int base = t*64;
  int s=0;
  for(int i=0;i<64;i++) s += deg[base+i];
  part[t]=s;
  __syncthreads();
  for(int off=1; off<1024; off<<=1){
    int v = (t>=off)? part[t-off] : 0;
    __syncthreads();
    part[t] += v;
    __syncthreads();
  }
  int run = (t==0)? 0 : part[t-1];
  for(int i=0;i<64;i++){
    int d = deg[base+i];
    offs[base+i] = run; cursor[base+i] = run;
    run += d;
  }
  if(t==1023) offs[NN] = run;
}

__global__ __launch_bounds__(256) void k_scatter(const int* __restrict__ ei,
      int* __restrict__ cursor, int* __restrict__ csr){
  int e = blockIdx.x*256 + threadIdx.x;
  if(e < NE){
    int d = ei[NE + e];
    int p = atomicAdd(&cursor[d], 1);
    csr[p] = ei[e];
  }
}

// ---------- conv0: agg[i] = max over in-edges of x[src], else 0 ----------
__global__ __launch_bounds__(256) void k_agg0(const float* __restrict__ x,
    const int* __restrict__ offs, const int* __restrict__ csr, float* __restrict__ agg0){
  int tid = blockIdx.x*256 + threadIdx.x;
  int node = tid>>4, q = tid&15;        // 16 threads (float4 lanes) per node
  int e0 = offs[node], e1 = offs[node+1];
  float4 acc = make_float4(0.f,0.f,0.f,0.f);
  if(e0 < e1){
    acc = make_float4(-INFINITY,-INFINITY,-INFINITY,-INFINITY);
    int e = e0;
    for(; e+3 < e1; e += 4){            // 4 independent gathers in flight
      int s0 = csr[e], s1 = csr[e+1], s2 = csr[e+2], s3 = csr[e+3];
      float4 v0 = ((const float4*)x)[s0*16 + q];
      float4 v1 = ((const float4*)x)[s1*16 + q];
      float4 v2 = ((const float4*)x)[s2*16 + q];
      float4 v3 = ((const float4*)x)[s3*16 + q];
      acc.x=fmaxf(acc.x,fmaxf(fmaxf(v0.x,v1.x),fmaxf(v2.x,v3.x)));
      acc.y=fmaxf(acc.y,fmaxf(fmaxf(v0.y,v1.y),fmaxf(v2.y,v3.y)));
      acc.z=fmaxf(acc.z,fmaxf(fmaxf(v0.z,v1.z),fmaxf(v2.z,v3.z)));
      acc.w=fmaxf(acc.w,fmaxf(fmaxf(v0.w,v1.w),fmaxf(v2.w,v3.w)));
    }
    for(; e < e1; e++){
      int s0 = csr[e];
      float4 v0 = ((const float4*)x)[s0*16 + q];
      acc.x=fmaxf(acc.x,v0.x); acc.y=fmaxf(acc.y,v0.y);
      acc.z=fmaxf(acc.z,v0.z); acc.w=fmaxf(acc.w,v0.w);
    }
  }
  ((float4*)agg0)[node*16 + q] = acc;
}

// ---------- conv0 matmul: cur = lrelu([agg0|x] @ [Wrel|Wroot]^T + b0) ----------
__global__ __launch_bounds__(256, 2) void k_conv0mm(
    const float* __restrict__ agg0, const float* __restrict__ x,
    const float* __restrict__ Wrel, const float* __restrict__ Wroot,
    const float* __restrict__ b0, float* __restrict__ cur,
    float* __restrict__ bnsum, float* __restrict__ bnsq){
  __shared__ float4 As[2048];   // 32 KB
  __shared__ float4 Ws[2048];   // 32 KB
  const int t = threadIdx.x;
  const int tn = t & 15;
  const int tc = t >> 4;
  float acc[8][8];
  #pragma unroll
  for(int i=0;i<8;i++)
    #pragma unroll
    for(int j=0;j<8;j++) acc[i][j]=0.f;

  const size_t tileoff = (size_t)blockIdx.x * 8192;
  #pragma unroll 1
  for(int ch=0; ch<2; ch++){
    const float4* gA = (const float4*)((ch==0? agg0 : x) + tileoff);
    const float4* gW = (const float4*)(ch==0? Wrel : Wroot);
    __syncthreads();
    #pragma unroll
    for(int i=0;i<8;i++){
      int idx = t + i*256;
      int n = idx>>4, k4 = idx&15;
      int sw = n*16 + ((k4 + (n>>3))&15);
      As[sw] = gA[idx];
      Ws[sw] = gW[idx];
    }
    __syncthreads();
    #pragma unroll 4
    for(int k4=0;k4<16;k4++){
      float4 a4[8], w4[8];
      #pragma unroll
      for(int i=0;i<8;i++) a4[i] = As[(tn*8+i)*16 + ((k4+tn)&15)];
      #pragma unroll
      for(int i=0;i<8;i++) w4[i] = Ws[(tc*8+i)*16 + ((k4+tc)&15)];
      #pragma unroll
      for(int i=0;i<8;i++)
        #pragma unroll
        for(int j=0;j<8;j++){
          acc[i][j] = fmaf(a4[i].x, w4[j].x, acc[i][j]);
          acc[i][j] = fmaf(a4[i].y, w4[j].y, acc[i][j]);
          acc[i][j] = fmaf(a4[i].z, w4[j].z, acc[i][j]);
          acc[i][j] = fmaf(a4[i].w, w4[j].w, acc[i][j]);
        }
    }
  }

  float bj[8];
  #pragma unroll
  for(int j=0;j<8;j++) bj[j] = b0[tc*8+j];
  float cs[8], cq[8];
  #pragma unroll
  for(int j=0;j<8;j++){ cs[j]=0.f; cq[j]=0.f; }
  const int nbase = blockIdx.x*128;
  #pragma unroll
  for(int i=0;i<8;i++){
    int node = nbase + tn*8 + i;
    float v[8];
    #pragma unroll
    for(int j=0;j<8;j++){
      v[j] = lrelu(acc[i][j] + bj[j]);
      cs[j] += v[j]; cq[j] += v[j]*v[j];
    }
    float4 o0 = make_float4(v[0],v[1],v[2],v[3]);
    float4 o1 = make_float4(v[4],v[5],v[6],v[7]);
    ((float4*)cur)[node*32 + tc*2 + 0] = o0;
    ((float4*)cur)[node*32 + tc*2 + 1] = o1;
  }
  __syncthreads();
  float* reds = (float*)As;
  float* redq = (float*)Ws;
  #pragma unroll
  for(int j=0;j<8;j++){
    reds[(tc*8+j)*16 + tn] = cs[j];
    redq[(tc*8+j)*16 + tn] = cq[j];
  }
  __syncthreads();
  if(t<128){
    float S=0.f, Q=0.f;
    #pragma unroll
    for(int i=0;i<16;i++){ S += reds[t*16+i]; Q += redq[t*16+i]; }
    atomicAdd(&bnsum[t], S);
    atomicAdd(&bnsq[t], Q);
  }
}

// ---------- streaming update + per-node pool scores ----------
// MODE 0: score-only pass over raw conv0 cur (bn0 scale folded into weights;
//         per-graph-constant offset cancels in softmax).
// MODE 1: cur = 0.5*bn0(cur) + 0.25*bn1(new), then scores with raw weights.
// MODE 2: cur = 0.5*cur + 0.25*bn1(new), then scores with raw weights.
// One float4 per thread (no unroll explosion); scores reduced over the 32
// threads owning a node via width-32 shuffle tree; lane 0 writes scores[n].
template<int MODE>
__global__ __launch_bounds__(256) void k_stream(
    float* __restrict__ cur, const float* __restrict__ onew,
    const unsigned char* __restrict__ keepin,
    const float* __restrict__ bnsA, const float* __restrict__ bnqA,
    const float* __restrict__ g1, const float* __restrict__ b1,
    const float* __restrict__ bns0, const float* __restrict__ bnq0,
    const float* __restrict__ g0, const float* __restrict__ b0bn,
    const float* __restrict__ pw, float* __restrict__ scores){
  __shared__ __align__(16) float w[4][128];
  __shared__ __align__(16) float sc1[128], of1[128], sc0[128], of0[128];
  const int t = threadIdx.x;
  if(t<128){
    if(MODE>=1){
      float mu = bnsA[t]*(1.0f/NN);
      float var = bnqA[t]*(1.0f/NN) - mu*mu;
      float s = g1[t]*rsqrtf(var+1e-5f);
      sc1[t]=s; of1[t]=b1[t]-mu*s;
    }
    if(MODE<=1){
      float mu0 = bns0[t]*(1.0f/NN);
      float var0 = bnq0[t]*(1.0f/NN) - mu0*mu0;
      float s0 = g0[t]*rsqrtf(var0+1e-5f);
      sc0[t]=s0; of0[t]=b0bn[t]-mu0*s0;
    }
  }
  __syncthreads();
  for(int i=t;i<512;i+=256){
    float wv = pw[i];
    if(MODE==0) wv *= sc0[i&127];
    w[i>>7][i&127]=wv;
  }
  __syncthreads();
  const int tid = blockIdx.x*256 + t;
  const int n = tid>>5, k = tid&31;
  float4 v = ((const float4*)cur)[tid];
  if(MODE>=1){
    const int h = k>>3;
    float4 nv = make_float4(0.f,0.f,0.f,0.f);
    if((keepin[n]>>h)&1) nv = ((const float4*)onew)[tid];
    float4 s1 = *(const float4*)&sc1[k*4];
    float4 o1 = *(const float4*)&of1[k*4];
    if(MODE==1){
      float4 s0 = *(const float4*)&sc0[k*4];
      float4 o0 = *(const float4*)&of0[k*4];
      v.x = 0.5f*(s0.x*v.x+o0.x) + 0.25f*(s1.x*nv.x+o1.x);
      v.y = 0.5f*(s0.y*v.y+o0.y) + 0.25f*(s1.y*nv.y+o1.y);
      v.z = 0.5f*(s0.z*v.z+o0.z) + 0.25f*(s1.z*nv.z+o1.z);
      v.w = 0.5f*(s0.w*v.w+o0.w) + 0.25f*(s1.w*nv.w+o1.w);
    } else {
      v.x = 0.5f*v.x + 0.25f*(s1.x*nv.x+o1.x);
      v.y = 0.5f*v.y + 0.25f*(s1.y*nv.y+o1.y);
      v.z = 0.5f*v.z + 0.25f*(s1.z*nv.z+o1.z);
      v.w = 0.5f*v.w + 0.25f*(s1.w*nv.w+o1.w);
    }
    ((float4*)cur)[tid] = v;
  }
  float sch[4];
  #pragma unroll
  for(int h2=0;h2<4;h2++){
    float4 wv = *(const float4*)&w[h2][k*4];
    sch[h2] = v.x*wv.x + v.y*wv.y + v.z*wv.z + v.w*wv.w;
  }
  #pragma unroll
  for(int o=16;o>0;o>>=1){
    #pragma unroll
    for(int h2=0;h2<4;h2++) sch[h2] += __shfl_down(sch[h2], o, 32);
  }
  if(k==0) ((float4*)scores)[n] = make_float4(sch[0],sch[1],sch[2],sch[3]);
}

// ---------- per-graph softmax + keep select from scores ----------
// NOTE: sm4 may alias scores — every thread reads its score before any write
// (block barriers inside the reductions enforce it; explicit barrier at end).
__global__ __launch_bounds__(256) void k_poolsel(const float* __restrict__ scores,
    float minscore, float* __restrict__ sm4, unsigned char* __restrict__ keep,
    int* __restrict__ cnt, int* __restrict__ wl){
  __shared__ float red[4];
  const int t = threadIdx.x, g = blockIdx.x, n = g*256 + t;
  float4 s4 = ((const float4*)scores)[n];
  float scv[4] = {s4.x, s4.y, s4.z, s4.w};
  float4 smout;
  unsigned kb = 0;
  #pragma unroll 1
  for(int h=0;h<4;h++){
    float m = blockMax4(scv[h], red);
    float e = expf(scv[h]-m);
    float ssum = blockSum4(e, red);
    float sm = e/(ssum + 1e-16f);
    float smax = blockMax4(sm, red);
    float thr = fminf(smax - 1e-7f, minscore);
    ((float*)&smout)[h] = sm;
    if(sm > thr){
      kb |= (1u<<h);
      int p = atomicAdd(cnt, 1);
      wl[p] = (h<<16) | n;
    }
  }
  __syncthreads();
  ((float4*)sm4)[n] = smout;
  keep[n] = (unsigned char)kb;
}

// ---------- block-layer GraphConv(max) on kept (head,node) items ----------
__global__ __launch_bounds__(256) void k_blockconv(const float* __restrict__ cur,
    const int* __restrict__ offs, const int* __restrict__ csr,
    const unsigned char* __restrict__ keep, const float* __restrict__ sm4,
    const int* __restrict__ cnt, const int* __restrict__ wl,
    const float* __restrict__ Wrel, const float* __restrict__ Wroot,
    const float* __restrict__ bias,
    float* __restrict__ onew, float* __restrict__ bnsum, float* __restrict__ bnsq,
    const float* __restrict__ bns0, const float* __restrict__ bnq0,
    const float* __restrict__ g0, const float* __restrict__ b0bn, int fold){
  __shared__ __align__(16) float aggs[8][128];
  __shared__ __align__(16) float xps[8][128];
  __shared__ __align__(16) float scv[128];
  __shared__ __align__(16) float ofv[128];
  const int t = threadIdx.x, grp = t>>5, lane = t&31;
  if(t<128){
    float sv = 1.f, ov = 0.f;
    if(fold){
      float mu = bns0[t]*(1.0f/NN);
      float var = bnq0[t]*(1.0f/NN) - mu*mu;
      sv = g0[t]*rsqrtf(var+1e-5f);
      ov = b0bn[t] - mu*sv;
    }
    scv[t]=sv; ofv[t]=ov;
  }
  __syncthreads();
  const float4 s4l = *(const float4*)&scv[lane*4];
  const float4 o4l = *(const float4*)&ofv[lane*4];
  const int total = *cnt;
  for(int item = blockIdx.x*8 + grp; item < total; item += gridDim.x*8){
    const int wv = wl[item];
    const int h = wv>>16, n = wv & 0xFFFF;
    const float smn = sm4[n*4+h];
    const int e0 = offs[n], e1 = offs[n+1];
    float4 acc = make_float4(-INFINITY,-INFINITY,-INFINITY,-INFINITY);
    bool any = false;
    for(int e=e0;e<e1;e++){
      int s = csr[e];
      if((keep[s]>>h)&1){
        any = true;
        float sv = sm4[s*4+h];
        float4 v = ((const float4*)cur)[s*32 + lane];
        v.x = (v.x*s4l.x + o4l.x)*sv; v.y = (v.y*s4l.y + o4l.y)*sv;
        v.z = (v.z*s4l.z + o4l.z)*sv; v.w = (v.w*s4l.w + o4l.w)*sv;
        acc.x = fmaxf(acc.x, v.x); acc.y = fmaxf(acc.y, v.y);
        acc.z = fmaxf(acc.z, v.z); acc.w = fmaxf(acc.w, v.w);
      }
    }
    if(!any) acc = make_float4(0.f,0.f,0.f,0.f);
    *(float4*)&aggs[grp][lane*4] = acc;
    float4 xv = ((const float4*)cur)[n*32 + lane];
    xv.x = (xv.x*s4l.x + o4l.x)*smn; xv.y = (xv.y*s4l.y + o4l.y)*smn;
    xv.z = (xv.z*s4l.z + o4l.z)*smn; xv.w = (xv.w*s4l.w + o4l.w)*smn;
    *(float4*)&xps[grp][lane*4] = xv;
    // half-wave group: LDS write->read is program-ordered within the wave
    const float* Wr = Wrel  + (size_t)(h*32+lane)*128;
    const float* Wo = Wroot + (size_t)(h*32+lane)*128;
    float o = bias[h*32+lane];
    for(int k=0;k<32;k++){
      float4 a  = *(const float4*)&aggs[grp][k*4];
      float4 xx = *(const float4*)&xps[grp][k*4];
      float4 wr = ((const float4*)Wr)[k];
      float4 wo = ((const float4*)Wo)[k];
      o += a.x*wr.x + a.y*wr.y + a.z*wr.z + a.w*wr.w;
      o += xx.x*wo.x + xx.y*wo.y + xx.z*wo.z + xx.w*wo.w;
    }
    o = lrelu(o);
    onew[(size_t)n*128 + h*32 + lane] = o;
    atomicAdd(&bnsum[h*32+lane], o);
    atomicAdd(&bnsq[h*32+lane], o*o);
  }
}

// ---------- classification heads (reads precomputed scores; gathers kept rows) ----------
__global__ __launch_bounds__(256) void k_cls(const float* __restrict__ cur,
    const float* __restrict__ scores,
    const float* __restrict__ gW1, const float* __restrict__ gb1,
    const float* __restrict__ gW2, const float* __restrict__ gb2,
    const float* __restrict__ fW1, const float* __restrict__ fb1,
    const float* __restrict__ fW2, const float* __restrict__ fb2,
    float* __restrict__ out){
  __shared__ float red[4];
  __shared__ int keptL[256];
  __shared__ float keptS[256];
  __shared__ float gateL[256];
  __shared__ __align__(16) float xk[128];
  __shared__ __align__(16) float pooled[128];
  __shared__ float yv[4];
  __shared__ int nkept;
  const int t = threadIdx.x, g = blockIdx.x;
  const int n = g*256 + t;
  float4 s4 = ((const float4*)scores)[n];
  float sc4[4] = {s4.x, s4.y, s4.z, s4.w};
  #pragma unroll 1
  for(int c=0;c<4;c++){
    float m = blockMax4(sc4[c], red);
    float e = expf(sc4[c]-m);
    float ssum = blockSum4(e, red);
    float sm = e/(ssum+1e-16f);
    float smax = blockMax4(sm, red);
    float thr = fminf(smax - 1e-7f, 0.8f);
    if(t==0) nkept = 0;
    __syncthreads();
    if(sm > thr){
      int p = atomicAdd(&nkept,1);
      keptL[p]=t; keptS[p]=sm;
    }
    __syncthreads();
    const int K = nkept;
    for(int k=0;k<K;k++){
      int ln = keptL[k]; float sv = keptS[k];
      if(t<32){
        float4 v = ((const float4*)(cur + (size_t)(g*256+ln)*128))[t];
        v.x*=sv; v.y*=sv; v.z*=sv; v.w*=sv;
        *(float4*)&xk[t*4] = v;
      }
      __syncthreads();
      float part = 0.f;
      if(t<128){
        const float* W = gW1 + (size_t)c*16384 + (size_t)t*128;
        float a = gb1[c*128+t];
        for(int f=0;f<32;f++){
          float4 xv = *(const float4*)&xk[f*4];
          float4 wv = ((const float4*)W)[f];
          a += xv.x*wv.x + xv.y*wv.y + xv.z*wv.z + xv.w*wv.w;
        }
        part = lrelu(a) * gW2[c*128+t];
      }
      float gs = blockSum4(part, red);
      if(t==0) gateL[k] = gs + gb2[c];
      __syncthreads();
    }
    float gv = (t<K)? gateL[t] : -INFINITY;
    float gm = blockMax4(gv, red);
    float ge = (t<K)? expf(gv-gm) : 0.f;
    float gsum = blockSum4(ge, red);
    if(t<K) gateL[t] = ge/(gsum+1e-16f);
    __syncthreads();
    if(t<128){
      float acc = 0.f;
      for(int k=0;k<K;k++)
        acc += gateL[k]*keptS[k]*cur[(size_t)(g*256+keptL[k])*128 + t];
      pooled[t]=acc;
    }
    __syncthreads();
    float part2=0.f;
    if(t<128){
      const float* F = fW1 + (size_t)c*16384 + (size_t)t*128;
      float a = fb1[c*128+t];
      for(int f=0;f<32;f++){
        float4 xv = *(const float4*)&pooled[f*4];
        float4 wv = ((const float4*)F)[f];
        a += xv.x*wv.x + xv.y*wv.y + xv.z*wv.z + xv.w*wv.w;
      }
      part2 = lrelu(a) * fW2[c*128+t];
    }
    float ysum = blockSum4(part2, red);
    if(t==0) yv[c] = ysum + fb2[c];
    __syncthreads();
  }
  if(t<4){
    float m = fmaxf(fmaxf(yv[0],yv[1]), fmaxf(yv[2],yv[3]));
    float l = logf(expf(yv[0]-m)+expf(yv[1]-m)+expf(yv[2]-m)+expf(yv[3]-m));
    out[g*4+t] = yv[t] - m - l;
  }
}

extern "C" void kernel_launch(void* const* d_in, const int* in_sizes, int n_in,
                              void* d_out, int out_size, void* d_ws, size_t ws_size,
                              hipStream_t stream){
  (void)in_sizes; (void)n_in; (void)out_size; (void)ws_size;
  const float* x     = (const float*)d_in[0];
  const int*   ei    = (const int*)d_in[1];
  const float* Wrel0 = (const float*)d_in[3];
  const float* Wroot0= (const float*)d_in[4];
  const float* b0    = (const float*)d_in[5];
  const float* bn0g  = (const float*)d_in[6];
  const float* bn0b  = (const float*)d_in[7];
  const float* bpw   = (const float*)d_in[8];
  const float* bWrel = (const float*)d_in[9];
  const float* bWroot= (const float*)d_in[10];
  const float* bbv   = (const float*)d_in[11];
  const float* bbng  = (const float*)d_in[12];
  const float* bbnb  = (const float*)d_in[13];
  const float* cpw   = (const float*)d_in[14];
  const float* gW1   = (const float*)d_in[15];
  const float* gb1   = (const float*)d_in[16];
  const float* gW2   = (const float*)d_in[17];
  const float* gb2   = (const float*)d_in[18];
  const float* fW1   = (const float*)d_in[19];
  const float* fb1   = (const float*)d_in[20];
  const float* fW2   = (const float*)d_in[21];
  const float* fb2   = (const float*)d_in[22];

  char* ws = (char*)d_ws;
  float* cur   = (float*)(ws + 0);                 // 33.55 MB
  float* onew  = (float*)(ws + 33554432ull);       // 33.55 MB (agg0 aliases it)
  float* agg0  = onew;
  int*   csr   = (int*)(ws + 67108864ull);         // 2 MB
  float* sm4   = (float*)(ws + 69206016ull);       // 1 MB (scores aliases it)
  float* scores= sm4;
  int*   wl    = (int*)(ws + 70254592ull);         // 1 MB
  int*   offs  = (int*)(ws + 71303168ull);         // 256 KB + pad
  int*   cursor= (int*)(ws + 71565568ull);         // 256 KB
  unsigned char* keep = (unsigned char*)(ws + 71827712ull); // 64 KB
  char*  Z     = ws + 71893248ull;                 // zero-init region
  int*   deg   = (int*)Z;
  float* bnsum0= (float*)(Z + 262144);
  float* bnsq0 = (float*)(Z + 262656);
  float* bnA   = (float*)(Z + 263168);
  float* bqA   = (float*)(Z + 263680);
  float* bnB   = (float*)(Z + 264192);
  float* bqB   = (float*)(Z + 264704);
  int*   cnt0  = (int*)(Z + 265216);
  int*   cnt1  = (int*)(Z + 265220);

  hipMemsetAsync(Z, 0, 265224, stream);

  // CSR by dst
  k_count  <<<2048,256,0,stream>>>(ei, deg);
  k_scan   <<<1,1024,0,stream>>>(deg, offs, cursor);
  k_scatter<<<2048,256,0,stream>>>(ei, cursor, csr);

  // conv0 -> lrelu (+ fused bn0 stats; bn0 apply folded into consumers)
  k_agg0    <<<4096,256,0,stream>>>(x, offs, csr, agg0);
  k_conv0mm <<<512,256,0,stream>>>(agg0, x, Wrel0, Wroot0, b0, cur, bnsum0, bnsq0);

  // pool layer 0: streamed scores (bn0-scale folded) + per-graph select
  k_stream<0><<<8192,256,0,stream>>>(cur, onew, keep, bnA, bqA, bbng, bbnb,
                                     bnsum0, bnsq0, bn0g, bn0b, bpw, scores);
  k_poolsel<<<256,256,0,stream>>>(scores, 0.7f, sm4, keep, cnt0, wl);

  // block layer 0 (bn0 folded into gathered rows)
  k_blockconv<<<256,256,0,stream>>>(cur, offs, csr, keep, sm4, cnt0, wl,
                                    bWrel, bWroot, bbv, onew, bnA, bqA,
                                    bnsum0, bnsq0, bn0g, bn0b, 1);

  // update layer 0 (materializes cur) + streamed scores for pool layer 1
  k_stream<1><<<8192,256,0,stream>>>(cur, onew, keep, bnA, bqA, bbng, bbnb,
                                     bnsum0, bnsq0, bn0g, bn0b, bpw + 512, scores);
  k_poolsel<<<256,256,0,stream>>>(scores, 0.7f, sm4, keep, cnt1, wl);

  // block layer 1 (no fold)
  k_blockconv<<<256,256,0,stream>>>(cur, offs, csr, keep, sm4, cnt1, wl,
                                    bWrel + 16384, bWroot + 16384, bbv + 128, onew, bnB, bqB,
                                    bnsum0, bnsq0, bn0g, bn0b, 0);

  // update layer 1 + streamed cls pool scores
  k_stream<2><<<8192,256,0,stream>>>(cur, onew, keep, bnB, bqB, bbng + 128, bbnb + 128,
                                     bnsum0, bnsq0, bn0g, bn0b, cpw, scores);

  // classification heads + log_softmax (kept-row gathers only)
  k_cls<<<256,256,0,stream>>>(cur, scores, gW1, gb1, gW2, gb2, fW1, fb1, fW2, fb2,
                              (float*)d_out);
}

// Round 5
// 405.426 us; speedup vs baseline: 1.7928x; 1.0411x over previous
//
#include <hip/hip_runtime.h>
#include <math.h>

#define NN 65536      // nodes
#define NE 524288     // edges
#define NG 256        // graphs (256 contiguous nodes each)
#define SLOPE 0.01f

__device__ __forceinline__ float lrelu(float v){ return v > 0.f ? v : SLOPE*v; }

// ---------- block reductions (256-thread blocks = 4 waves) ----------
__device__ __forceinline__ float blockMax4(float v, float* s4){
  #pragma unroll
  for(int o=32;o>0;o>>=1) v = fmaxf(v, __shfl_down(v, o, 64));
  int t = threadIdx.x;
  __syncthreads();
  if((t&63)==0) s4[t>>6] = v;
  __syncthreads();
  return fmaxf(fmaxf(s4[0], s4[1]), fmaxf(s4[2], s4[3]));
}
__device__ __forceinline__ float blockSum4(float v, float* s4){
  #pragma unroll
  for(int o=32;o>0;o>>=1) v += __shfl_down(v, o, 64);
  int t = threadIdx.x;
  __syncthreads();
  if((t&63)==0) s4[t>>6] = v;
  __syncthreads();
  return (s4[0]+s4[1])+(s4[2]+s4[3]);
}

// ---------- CSR build (by dst) ----------
__global__ __launch_bounds__(256) void k_count(const int* __restrict__ ei, int* __restrict__ deg){
  int e = blockIdx.x*256 + threadIdx.x;
  if(e < NE) atomicAdd(&deg[ei[NE + e]], 1);
}

__global__ __launch_bounds__(1024) void k_scan(const int* __restrict__ deg,
      int* __restrict__ offs, int* __restrict__ cursor){
  __shared__ int part[1024];
  int t = threadIdx.x;
  int base = t*64;
  int s=0;
  for(int i=0;i<64;i++) s += deg[base+i];
  part[t]=s;
  __syncthreads();
  for(int off=1; off<1024; off<<=1){
    int v = (t>=off)? part[t-off] : 0;
    __syncthreads();
    part[t] += v;
    __syncthreads();
  }
  int run = (t==0)? 0 : part[t-1];
  for(int i=0;i<64;i++){
    int d = deg[base+i];
    offs[base+i] = run; cursor[base+i] = run;
    run += d;
  }
  if(t==1023) offs[NN] = run;
}

__global__ __launch_bounds__(256) void k_scatter(const int* __restrict__ ei,
      int* __restrict__ cursor, int* __restrict__ csr){
  int e = blockIdx.x*256 + threadIdx.x;
  if(e < NE){
    int d = ei[NE + e];
    int p = atomicAdd(&cursor[d], 1);
    csr[p] = ei[e];
  }
}

// ---------- conv0: agg[i] = max over in-edges of x[src], else 0 ----------
__global__ __launch_bounds__(256) void k_agg0(const float* __restrict__ x,
    const int* __restrict__ offs, const int* __restrict__ csr, float* __restrict__ agg0){
  int tid = blockIdx.x*256 + threadIdx.x;
  int node = tid>>4, q = tid&15;        // 16 threads (float4 lanes) per node
  int e0 = offs[node], e1 = offs[node+1];
  float4 acc = make_float4(0.f,0.f,0.f,0.f);
  if(e0 < e1){
    acc = make_float4(-INFINITY,-INFINITY,-INFINITY,-INFINITY);
    int e = e0;
    for(; e+3 < e1; e += 4){            // 4 independent gathers in flight
      int s0 = csr[e], s1 = csr[e+1], s2 = csr[e+2], s3 = csr[e+3];
      float4 v0 = ((const float4*)x)[s0*16 + q];
      float4 v1 = ((const float4*)x)[s1*16 + q];
      float4 v2 = ((const float4*)x)[s2*16 + q];
      float4 v3 = ((const float4*)x)[s3*16 + q];
      acc.x=fmaxf(acc.x,fmaxf(fmaxf(v0.x,v1.x),fmaxf(v2.x,v3.x)));
      acc.y=fmaxf(acc.y,fmaxf(fmaxf(v0.y,v1.y),fmaxf(v2.y,v3.y)));
      acc.z=fmaxf(acc.z,fmaxf(fmaxf(v0.z,v1.z),fmaxf(v2.z,v3.z)));
      acc.w=fmaxf(acc.w,fmaxf(fmaxf(v0.w,v1.w),fmaxf(v2.w,v3.w)));
    }
    for(; e < e1; e++){
      int s0 = csr[e];
      float4 v0 = ((const float4*)x)[s0*16 + q];
      acc.x=fmaxf(acc.x,v0.x); acc.y=fmaxf(acc.y,v0.y);
      acc.z=fmaxf(acc.z,v0.z); acc.w=fmaxf(acc.w,v0.w);
    }
  }
  ((float4*)agg0)[node*16 + q] = acc;
}

// ---------- conv0 matmul: cur = lrelu([agg0|x] @ [Wrel|Wroot]^T + b0) ----------
__global__ __launch_bounds__(256, 2) void k_conv0mm(
    const float* __restrict__ agg0, const float* __restrict__ x,
    const float* __restrict__ Wrel, const float* __restrict__ Wroot,
    const float* __restrict__ b0, float* __restrict__ cur,
    float* __restrict__ bnsum, float* __restrict__ bnsq){
  __shared__ float4 As[2048];   // 32 KB
  __shared__ float4 Ws[2048];   // 32 KB
  const int t = threadIdx.x;
  const int tn = t & 15;
  const int tc = t >> 4;
  float acc[8][8];
  #pragma unroll
  for(int i=0;i<8;i++)
    #pragma unroll
    for(int j=0;j<8;j++) acc[i][j]=0.f;

  const size_t tileoff = (size_t)blockIdx.x * 8192;
  #pragma unroll 1
  for(int ch=0; ch<2; ch++){
    const float4* gA = (const float4*)((ch==0? agg0 : x) + tileoff);
    const float4* gW = (const float4*)(ch==0? Wrel : Wroot);
    __syncthreads();
    #pragma unroll
    for(int i=0;i<8;i++){
      int idx = t + i*256;
      int n = idx>>4, k4 = idx&15;
      int sw = n*16 + ((k4 + (n>>3))&15);
      As[sw] = gA[idx];
      Ws[sw] = gW[idx];
    }
    __syncthreads();
    #pragma unroll 4
    for(int k4=0;k4<16;k4++){
      float4 a4[8], w4[8];
      #pragma unroll
      for(int i=0;i<8;i++) a4[i] = As[(tn*8+i)*16 + ((k4+tn)&15)];
      #pragma unroll
      for(int i=0;i<8;i++) w4[i] = Ws[(tc*8+i)*16 + ((k4+tc)&15)];
      #pragma unroll
      for(int i=0;i<8;i++)
        #pragma unroll
        for(int j=0;j<8;j++){
          acc[i][j] = fmaf(a4[i].x, w4[j].x, acc[i][j]);
          acc[i][j] = fmaf(a4[i].y, w4[j].y, acc[i][j]);
          acc[i][j] = fmaf(a4[i].z, w4[j].z, acc[i][j]);
          acc[i][j] = fmaf(a4[i].w, w4[j].w, acc[i][j]);
        }
    }
  }

  float bj[8];
  #pragma unroll
  for(int j=0;j<8;j++) bj[j] = b0[tc*8+j];
  float cs[8], cq[8];
  #pragma unroll
  for(int j=0;j<8;j++){ cs[j]=0.f; cq[j]=0.f; }
  const int nbase = blockIdx.x*128;
  #pragma unroll
  for(int i=0;i<8;i++){
    int node = nbase + tn*8 + i;
    float v[8];
    #pragma unroll
    for(int j=0;j<8;j++){
      v[j] = lrelu(acc[i][j] + bj[j]);
      cs[j] += v[j]; cq[j] += v[j]*v[j];
    }
    float4 o0 = make_float4(v[0],v[1],v[2],v[3]);
    float4 o1 = make_float4(v[4],v[5],v[6],v[7]);
    ((float4*)cur)[node*32 + tc*2 + 0] = o0;
    ((float4*)cur)[node*32 + tc*2 + 1] = o1;
  }
  __syncthreads();
  float* reds = (float*)As;
  float* redq = (float*)Ws;
  #pragma unroll
  for(int j=0;j<8;j++){
    reds[(tc*8+j)*16 + tn] = cs[j];
    redq[(tc*8+j)*16 + tn] = cq[j];
  }
  __syncthreads();
  if(t<128){
    float S=0.f, Q=0.f;
    #pragma unroll
    for(int i=0;i<16;i++){ S += reds[t*16+i]; Q += redq[t*16+i]; }
    atomicAdd(&bnsum[t], S);
    atomicAdd(&bnsq[t], Q);
  }
}

// ---------- streaming update + per-node pool scores ----------
template<int MODE>
__global__ __launch_bounds__(256) void k_stream(
    float* __restrict__ cur, const float* __restrict__ onew,
    const unsigned char* __restrict__ keepin,
    const float* __restrict__ bnsA, const float* __restrict__ bnqA,
    const float* __restrict__ g1, const float* __restrict__ b1,
    const float* __restrict__ bns0, const float* __restrict__ bnq0,
    const float* __restrict__ g0, const float* __restrict__ b0bn,
    const float* __restrict__ pw, float* __restrict__ scores){
  __shared__ __align__(16) float w[4][128];
  __shared__ __align__(16) float sc1[128], of1[128], sc0[128], of0[128];
  const int t = threadIdx.x;
  if(t<128){
    if(MODE>=1){
      float mu = bnsA[t]*(1.0f/NN);
      float var = bnqA[t]*(1.0f/NN) - mu*mu;
      float s = g1[t]*rsqrtf(var+1e-5f);
      sc1[t]=s; of1[t]=b1[t]-mu*s;
    }
    if(MODE<=1){
      float mu0 = bns0[t]*(1.0f/NN);
      float var0 = bnq0[t]*(1.0f/NN) - mu0*mu0;
      float s0 = g0[t]*rsqrtf(var0+1e-5f);
      sc0[t]=s0; of0[t]=b0bn[t]-mu0*s0;
    }
  }
  __syncthreads();
  for(int i=t;i<512;i+=256){
    float wv = pw[i];
    if(MODE==0) wv *= sc0[i&127];
    w[i>>7][i&127]=wv;
  }
  __syncthreads();
  const int tid = blockIdx.x*256 + t;
  const int n = tid>>5, k = tid&31;
  float4 v = ((const float4*)cur)[tid];
  if(MODE>=1){
    const int h = k>>3;
    float4 nv = make_float4(0.f,0.f,0.f,0.f);
    if((keepin[n]>>h)&1) nv = ((const float4*)onew)[tid];
    float4 s1 = *(const float4*)&sc1[k*4];
    float4 o1 = *(const float4*)&of1[k*4];
    if(MODE==1){
      float4 s0 = *(const float4*)&sc0[k*4];
      float4 o0 = *(const float4*)&of0[k*4];
      v.x = 0.5f*(s0.x*v.x+o0.x) + 0.25f*(s1.x*nv.x+o1.x);
      v.y = 0.5f*(s0.y*v.y+o0.y) + 0.25f*(s1.y*nv.y+o1.y);
      v.z = 0.5f*(s0.z*v.z+o0.z) + 0.25f*(s1.z*nv.z+o1.z);
      v.w = 0.5f*(s0.w*v.w+o0.w) + 0.25f*(s1.w*nv.w+o1.w);
    } else {
      v.x = 0.5f*v.x + 0.25f*(s1.x*nv.x+o1.x);
      v.y = 0.5f*v.y + 0.25f*(s1.y*nv.y+o1.y);
      v.z = 0.5f*v.z + 0.25f*(s1.z*nv.z+o1.z);
      v.w = 0.5f*v.w + 0.25f*(s1.w*nv.w+o1.w);
    }
    ((float4*)cur)[tid] = v;
  }
  float sch[4];
  #pragma unroll
  for(int h2=0;h2<4;h2++){
    float4 wv = *(const float4*)&w[h2][k*4];
    sch[h2] = v.x*wv.x + v.y*wv.y + v.z*wv.z + v.w*wv.w;
  }
  #pragma unroll
  for(int o=16;o>0;o>>=1){
    #pragma unroll
    for(int h2=0;h2<4;h2++) sch[h2] += __shfl_down(sch[h2], o, 32);
  }
  if(k==0) ((float4*)scores)[n] = make_float4(sch[0],sch[1],sch[2],sch[3]);
}

// ---------- per-graph softmax + keep select from scores ----------
__global__ __launch_bounds__(256) void k_poolsel(const float* __restrict__ scores,
    float minscore, float* __restrict__ sm4, unsigned char* __restrict__ keep,
    int* __restrict__ cnt, int* __restrict__ wl){
  __shared__ float red[4];
  const int t = threadIdx.x, g = blockIdx.x, n = g*256 + t;
  float4 s4 = ((const float4*)scores)[n];
  float scv[4] = {s4.x, s4.y, s4.z, s4.w};
  float4 smout;
  unsigned kb = 0;
  #pragma unroll 1
  for(int h=0;h<4;h++){
    float m = blockMax4(scv[h], red);
    float e = expf(scv[h]-m);
    float ssum = blockSum4(e, red);
    float sm = e/(ssum + 1e-16f);
    float smax = blockMax4(sm, red);
    float thr = fminf(smax - 1e-7f, minscore);
    ((float*)&smout)[h] = sm;
    if(sm > thr){
      kb |= (1u<<h);
      int p = atomicAdd(cnt, 1);
      wl[p] = (h<<16) | n;
    }
  }
  __syncthreads();
  ((float4*)sm4)[n] = smout;
  keep[n] = (unsigned char)kb;
}

// ---------- block-layer GraphConv(max) on kept (head,node) items ----------
__global__ __launch_bounds__(256) void k_blockconv(const float* __restrict__ cur,
    const int* __restrict__ offs, const int* __restrict__ csr,
    const unsigned char* __restrict__ keep, const float* __restrict__ sm4,
    const int* __restrict__ cnt, const int* __restrict__ wl,
    const float* __restrict__ Wrel, const float* __restrict__ Wroot,
    const float* __restrict__ bias,
    float* __restrict__ onew, float* __restrict__ bnsum, float* __restrict__ bnsq,
    const float* __restrict__ bns0, const float* __restrict__ bnq0,
    const float* __restrict__ g0, const float* __restrict__ b0bn, int fold){
  __shared__ __align__(16) float aggs[8][128];
  __shared__ __align__(16) float xps[8][128];
  __shared__ __align__(16) float scv[128];
  __shared__ __align__(16) float ofv[128];
  const int t = threadIdx.x, grp = t>>5, lane = t&31;
  if(t<128){
    float sv = 1.f, ov = 0.f;
    if(fold){
      float mu = bns0[t]*(1.0f/NN);
      float var = bnq0[t]*(1.0f/NN) - mu*mu;
      sv = g0[t]*rsqrtf(var+1e-5f);
      ov = b0bn[t] - mu*sv;
    }
    scv[t]=sv; ofv[t]=ov;
  }
  __syncthreads();
  const float4 s4l = *(const float4*)&scv[lane*4];
  const float4 o4l = *(const float4*)&ofv[lane*4];
  const int total = *cnt;
  for(int item = blockIdx.x*8 + grp; item < total; item += gridDim.x*8){
    const int wv = wl[item];
    const int h = wv>>16, n = wv & 0xFFFF;
    const float smn = sm4[n*4+h];
    const int e0 = offs[n], e1 = offs[n+1];
    float4 acc = make_float4(-INFINITY,-INFINITY,-INFINITY,-INFINITY);
    bool any = false;
    for(int e=e0;e<e1;e++){
      int s = csr[e];
      if((keep[s]>>h)&1){
        any = true;
        float sv = sm4[s*4+h];
        float4 v = ((const float4*)cur)[s*32 + lane];
        v.x = (v.x*s4l.x + o4l.x)*sv; v.y = (v.y*s4l.y + o4l.y)*sv;
        v.z = (v.z*s4l.z + o4l.z)*sv; v.w = (v.w*s4l.w + o4l.w)*sv;
        acc.x = fmaxf(acc.x, v.x); acc.y = fmaxf(acc.y, v.y);
        acc.z = fmaxf(acc.z, v.z); acc.w = fmaxf(acc.w, v.w);
      }
    }
    if(!any) acc = make_float4(0.f,0.f,0.f,0.f);
    *(float4*)&aggs[grp][lane*4] = acc;
    float4 xv = ((const float4*)cur)[n*32 + lane];
    xv.x = (xv.x*s4l.x + o4l.x)*smn; xv.y = (xv.y*s4l.y + o4l.y)*smn;
    xv.z = (xv.z*s4l.z + o4l.z)*smn; xv.w = (xv.w*s4l.w + o4l.w)*smn;
    *(float4*)&xps[grp][lane*4] = xv;
    // half-wave group: LDS write->read is program-ordered within the wave
    const float* Wr = Wrel  + (size_t)(h*32+lane)*128;
    const float* Wo = Wroot + (size_t)(h*32+lane)*128;
    float o = bias[h*32+lane];
    for(int k=0;k<32;k++){
      float4 a  = *(const float4*)&aggs[grp][k*4];
      float4 xx = *(const float4*)&xps[grp][k*4];
      float4 wr = ((const float4*)Wr)[k];
      float4 wo = ((const float4*)Wo)[k];
      o += a.x*wr.x + a.y*wr.y + a.z*wr.z + a.w*wr.w;
      o += xx.x*wo.x + xx.y*wo.y + xx.z*wo.z + xx.w*wo.w;
    }
    o = lrelu(o);
    onew[(size_t)n*128 + h*32 + lane] = o;
    atomicAdd(&bnsum[h*32+lane], o);
    atomicAdd(&bnsq[h*32+lane], o*o);
  }
}

// ---------- classification: one block per (graph, class) ----------
__global__ __launch_bounds__(256) void k_cls2(const float* __restrict__ cur,
    const float* __restrict__ scores,
    const float* __restrict__ gW1, const float* __restrict__ gb1,
    const float* __restrict__ gW2, const float* __restrict__ gb2,
    const float* __restrict__ fW1, const float* __restrict__ fb1,
    const float* __restrict__ fW2, const float* __restrict__ fb2,
    float* __restrict__ yws){
  __shared__ float red[4];
  __shared__ int keptL[256];
  __shared__ float keptS[256];
  __shared__ float gateL[256];
  __shared__ __align__(16) float xk[128];
  __shared__ __align__(16) float pooled[128];
  __shared__ int nkept;
  const int t = threadIdx.x;
  const int g = blockIdx.x >> 2, c = blockIdx.x & 3;
  const int n = g*256 + t;
  float sc = scores[n*4 + c];
  float m = blockMax4(sc, red);
  float e = expf(sc-m);
  float ssum = blockSum4(e, red);
  float sm = e/(ssum+1e-16f);
  float smax = blockMax4(sm, red);
  float thr = fminf(smax - 1e-7f, 0.8f);
  if(t==0) nkept = 0;
  __syncthreads();
  if(sm > thr){
    int p = atomicAdd(&nkept,1);
    keptL[p]=t; keptS[p]=sm;
  }
  __syncthreads();
  const int K = nkept;
  for(int k=0;k<K;k++){
    int ln = keptL[k]; float sv = keptS[k];
    if(t<32){
      float4 v = ((const float4*)(cur + (size_t)(g*256+ln)*128))[t];
      v.x*=sv; v.y*=sv; v.z*=sv; v.w*=sv;
      *(float4*)&xk[t*4] = v;
    }
    __syncthreads();
    float part = 0.f;
    if(t<128){
      const float* W = gW1 + (size_t)c*16384 + (size_t)t*128;
      float a = gb1[c*128+t];
      for(int f=0;f<32;f++){
        float4 xv = *(const float4*)&xk[f*4];
        float4 wv = ((const float4*)W)[f];
        a += xv.x*wv.x + xv.y*wv.y + xv.z*wv.z + xv.w*wv.w;
      }
      part = lrelu(a) * gW2[c*128+t];
    }
    float gs = blockSum4(part, red);
    if(t==0) gateL[k] = gs + gb2[c];
    __syncthreads();
  }
  float gv = (t<K)? gateL[t] : -INFINITY;
  float gm = blockMax4(gv, red);
  float ge = (t<K)? expf(gv-gm) : 0.f;
  float gsum = blockSum4(ge, red);
  if(t<K) gateL[t] = ge/(gsum+1e-16f);
  __syncthreads();
  if(t<128){
    float acc = 0.f;
    for(int k=0;k<K;k++)
      acc += gateL[k]*keptS[k]*cur[(size_t)(g*256+keptL[k])*128 + t];
    pooled[t]=acc;
  }
  __syncthreads();
  float part2=0.f;
  if(t<128){
    const float* F = fW1 + (size_t)c*16384 + (size_t)t*128;
    float a = fb1[c*128+t];
    for(int f=0;f<32;f++){
      float4 xv = *(const float4*)&pooled[f*4];
      float4 wv = ((const float4*)F)[f];
      a += xv.x*wv.x + xv.y*wv.y + xv.z*wv.z + xv.w*wv.w;
    }
    part2 = lrelu(a) * fW2[c*128+t];
  }
  float ysum = blockSum4(part2, red);
  if(t==0) yws[g*4+c] = ysum + fb2[c];
}

// ---------- final per-graph log_softmax over 4 class logits ----------
__global__ __launch_bounds__(256) void k_clsfin(const float* __restrict__ yws,
                                                float* __restrict__ out){
  const int g = threadIdx.x;            // single block, thread = graph
  float4 y = ((const float4*)yws)[g];
  float m = fmaxf(fmaxf(y.x,y.y), fmaxf(y.z,y.w));
  float l = logf(expf(y.x-m)+expf(y.y-m)+expf(y.z-m)+expf(y.w-m));
  float4 o = make_float4(y.x-m-l, y.y-m-l, y.z-m-l, y.w-m-l);
  ((float4*)out)[g] = o;
}

extern "C" void kernel_launch(void* const* d_in, const int* in_sizes, int n_in,
                              void* d_out, int out_size, void* d_ws, size_t ws_size,
                              hipStream_t stream){
  (void)in_sizes; (void)n_in; (void)out_size; (void)ws_size;
  const float* x     = (const float*)d_in[0];
  const int*   ei    = (const int*)d_in[1];
  const float* Wrel0 = (const float*)d_in[3];
  const float* Wroot0= (const float*)d_in[4];
  const float* b0    = (const float*)d_in[5];
  const float* bn0g  = (const float*)d_in[6];
  const float* bn0b  = (const float*)d_in[7];
  const float* bpw   = (const float*)d_in[8];
  const float* bWrel = (const float*)d_in[9];
  const float* bWroot= (const float*)d_in[10];
  const float* bbv   = (const float*)d_in[11];
  const float* bbng  = (const float*)d_in[12];
  const float* bbnb  = (const float*)d_in[13];
  const float* cpw   = (const float*)d_in[14];
  const float* gW1   = (const float*)d_in[15];
  const float* gb1   = (const float*)d_in[16];
  const float* gW2   = (const float*)d_in[17];
  const float* gb2   = (const float*)d_in[18];
  const float* fW1   = (const float*)d_in[19];
  const float* fb1   = (const float*)d_in[20];
  const float* fW2   = (const float*)d_in[21];
  const float* fb2   = (const float*)d_in[22];

  char* ws = (char*)d_ws;
  float* cur   = (float*)(ws + 0);                 // 33.55 MB
  float* onew  = (float*)(ws + 33554432ull);       // 33.55 MB (agg0 aliases it)
  float* agg0  = onew;
  int*   csr   = (int*)(ws + 67108864ull);         // 2 MB
  float* sm4   = (float*)(ws + 69206016ull);       // 1 MB (scores aliases it)
  float* scores= sm4;
  int*   wl    = (int*)(ws + 70254592ull);         // 1 MB
  int*   offs  = (int*)(ws + 71303168ull);         // 256 KB + pad
  int*   cursor= (int*)(ws + 71565568ull);         // 256 KB
  unsigned char* keep = (unsigned char*)(ws + 71827712ull); // 64 KB
  char*  Z     = ws + 71893248ull;                 // zero-init region
  int*   deg   = (int*)Z;
  float* bnsum0= (float*)(Z + 262144);
  float* bnsq0 = (float*)(Z + 262656);
  float* bnA   = (float*)(Z + 263168);
  float* bqA   = (float*)(Z + 263680);
  float* bnB   = (float*)(Z + 264192);
  float* bqB   = (float*)(Z + 264704);
  int*   cnt0  = (int*)(Z + 265216);
  int*   cnt1  = (int*)(Z + 265220);
  float* yws   = (float*)(Z + 266240);             // 4 KB, written before read

  hipMemsetAsync(Z, 0, 265224, stream);

  // CSR by dst
  k_count  <<<2048,256,0,stream>>>(ei, deg);
  k_scan   <<<1,1024,0,stream>>>(deg, offs, cursor);
  k_scatter<<<2048,256,0,stream>>>(ei, cursor, csr);

  // conv0 -> lrelu (+ fused bn0 stats; bn0 apply folded into consumers)
  k_agg0    <<<4096,256,0,stream>>>(x, offs, csr, agg0);
  k_conv0mm <<<512,256,0,stream>>>(agg0, x, Wrel0, Wroot0, b0, cur, bnsum0, bnsq0);

  // pool layer 0: streamed scores (bn0-scale folded) + per-graph select
  k_stream<0><<<8192,256,0,stream>>>(cur, onew, keep, bnA, bqA, bbng, bbnb,
                                     bnsum0, bnsq0, bn0g, bn0b, bpw, scores);
  k_poolsel<<<256,256,0,stream>>>(scores, 0.7f, sm4, keep, cnt0, wl);

  // block layer 0 (bn0 folded into gathered rows)
  k_blockconv<<<256,256,0,stream>>>(cur, offs, csr, keep, sm4, cnt0, wl,
                                    bWrel, bWroot, bbv, onew, bnA, bqA,
                                    bnsum0, bnsq0, bn0g, bn0b, 1);

  // update layer 0 (materializes cur) + streamed scores for pool layer 1
  k_stream<1><<<8192,256,0,stream>>>(cur, onew, keep, bnA, bqA, bbng, bbnb,
                                     bnsum0, bnsq0, bn0g, bn0b, bpw + 512, scores);
  k_poolsel<<<256,256,0,stream>>>(scores, 0.7f, sm4, keep, cnt1, wl);

  // block layer 1 (no fold)
  k_blockconv<<<256,256,0,stream>>>(cur, offs, csr, keep, sm4, cnt1, wl,
                                    bWrel + 16384, bWroot + 16384, bbv + 128, onew, bnB, bqB,
                                    bnsum0, bnsq0, bn0g, bn0b, 0);

  // update layer 1 + streamed cls pool scores
  k_stream<2><<<8192,256,0,stream>>>(cur, onew, keep, bnB, bqB, bbng + 128, bbnb + 128,
                                     bnsum0, bnsq0, bn0g, bn0b, cpw, scores);

  // classification heads: block per (graph, class), then 4-way log_softmax
  k_cls2<<<1024,256,0,stream>>>(cur, scores, gW1, gb1, gW2, gb2,
                                fW1, fb1, fW2, fb2, yws);
  k_clsfin<<<1,256,0,stream>>>(yws, (float*)d_out);
}